// Round 11
// baseline (28513.303 us; speedup 1.0000x reference)
//
#include <hip/hip_runtime.h>

// 2-layer GRU, I=8, H=128, T=32768 steps, out = final h1 (128 f32).
// Launch-level pipeline (no flags/spins; proven r7-r9). Launch k, disjoint blocks:
//   blocks 2-4 (army): phase A: gi0 = w_ih0@x + b for chunk k (x-only, ahead)
//                      phase B: gi1 = w_ih1@h0 + b for chunk k-2
//   block 0 (l0): layer-0 recurrence, chunk k-1 (consumes gi0, publishes h0 ring)
//   block 1 (l1): layer-1 recurrence, chunk k-3 (consumes gi1, writes out at end)
// r10 post-mortem: RA is pressure-driven when UNCONSTRAINED (m97: 164 VGPR, no
// attributes, no asm pinning); our attributes+asm-pinning were hurting. This
// round: plain loads, plain __launch_bounds__(512), demand ~150, 56KB LDS
// (pad caps occupancy at 2 blocks/CU; stays under the 64KB static-safe line).

#define T_STEPS 32768
#define HDIM 128
#define CH 1024
#define NC (T_STEPS / CH)
#define GS 8

typedef __attribute__((ext_vector_type(2))) float f32x2;
typedef __attribute__((ext_vector_type(4))) float f32x4;

__device__ __forceinline__ f32x2 lo2(f32x4 v) { return __builtin_shufflevector(v, v, 0, 1); }
__device__ __forceinline__ f32x2 hi2(f32x4 v) { return __builtin_shufflevector(v, v, 2, 3); }
__device__ __forceinline__ void pkfma(f32x2& acc, f32x2 a, f32x2 b) {
  asm("v_pk_fma_f32 %0, %1, %2, %0" : "+v"(acc) : "v"(a), "v"(b));
}
__device__ __forceinline__ float sigm(float x) {
  return __fdividef(1.f, 1.f + __expf(-x));
}
__device__ __forceinline__ float tanh_fast(float x) {
  x = fminf(15.f, fmaxf(-15.f, x));
  float e = __expf(2.f * x);
  return (e - 1.f) * __fdividef(1.f, e + 1.f);
}
// 8-lane butterfly: xor1 (quad_perm 0xB1), xor2 (0x4E), half-mirror (0x141).
__device__ __forceinline__ float red8(float v) {
  int t = __builtin_amdgcn_mov_dpp(__builtin_bit_cast(int, v), 0xB1, 0xF, 0xF, true);
  v += __builtin_bit_cast(float, t);
  t = __builtin_amdgcn_mov_dpp(__builtin_bit_cast(int, v), 0x4E, 0xF, 0xF, true);
  v += __builtin_bit_cast(float, t);
  t = __builtin_amdgcn_mov_dpp(__builtin_bit_cast(int, v), 0x141, 0xF, 0xF, true);
  v += __builtin_bit_cast(float, t);
  return v;
}

// ============== unified recurrence (l0 and l1 are the same machine) ==============
// Thread: cs = tid&7 -> cols {8cs..8cs+8} u {64+8cs..}; g = tid>>3 -> units 2g,2g+1.
// Row order in W[]: u0r, u1r, u0z, u1z, u0n, u1n. gi stream carries biases for
// r,z,n-input parts; only b_hh[n] stays separate (r scales the h-part only).
__device__ __forceinline__ void rec_layer(const float* __restrict__ Whh,
                                          const float* __restrict__ bhh,
                                          const float* __restrict__ rz,
                                          const float* __restrict__ nb,
                                          float* __restrict__ hstate,
                                          float* __restrict__ h0out,
                                          float* __restrict__ outp, int c) {
  __shared__ __align__(16) float hbuf[2][HDIM];
  const int tid = threadIdx.x, cs = tid & 7, g = tid >> 3;
  const int u0 = 2 * g, u1 = u0 + 1;

  f32x4 W[6][4];
  {
    const int rows[6] = {u0, u1, u0 + 128, u1 + 128, u0 + 256, u1 + 256};
    #pragma unroll
    for (int rr = 0; rr < 6; ++rr) {
      const float* wp = Whh + (size_t)rows[rr] * 128 + 8 * cs;
      W[rr][0] = *(const f32x4*)(wp);
      W[rr][1] = *(const f32x4*)(wp + 4);
      W[rr][2] = *(const f32x4*)(wp + 64);
      W[rr][3] = *(const f32x4*)(wp + 68);
    }
  }
  const float bhn0 = bhh[u0 + 256], bhn1 = bhh[u1 + 256];

  float hp0 = 0.f, hp1 = 0.f;
  if (c > 0) { hp0 = hstate[u0]; hp1 = hstate[u1]; }
  if (cs == 0) { f32x2 hw = {hp0, hp1}; *(f32x2*)&hbuf[0][u0] = hw; }
  // gate-stream prefetch, 2 steps deep (parity slots A=even, B=odd)
  f32x4 gvA = *(const f32x4*)(rz + 4 * g);
  f32x2 gnA = *(const f32x2*)(nb + 2 * g);
  f32x4 gvB = *(const f32x4*)(rz + 256 + 4 * g);
  f32x2 gnB = *(const f32x2*)(nb + 128 + 2 * g);
  __syncthreads();

#define DOTROW(C, RR) \
  pkfma(C, lo2(W[RR][0]), lo2(hA)); pkfma(C, hi2(W[RR][0]), hi2(hA)); \
  pkfma(C, lo2(W[RR][1]), lo2(hB)); pkfma(C, hi2(W[RR][1]), hi2(hB)); \
  pkfma(C, lo2(W[RR][2]), lo2(hC)); pkfma(C, hi2(W[RR][2]), hi2(hC)); \
  pkfma(C, lo2(W[RR][3]), lo2(hD)); pkfma(C, hi2(W[RR][3]), hi2(hD));

#define RSTEP(PR, GV, GN) do { \
    const f32x4 hA = *(const f32x4*)&hbuf[PR][8 * cs]; \
    const f32x4 hB = *(const f32x4*)&hbuf[PR][8 * cs + 4]; \
    const f32x4 hC = *(const f32x4*)&hbuf[PR][64 + 8 * cs]; \
    const f32x4 hD = *(const f32x4*)&hbuf[PR][64 + 8 * cs + 4]; \
    f32x2 c0 = {0.f, 0.f}, c1 = c0, c2 = c0, c3 = c0, c4 = c0, c5 = c0; \
    DOTROW(c0, 0) DOTROW(c1, 1) DOTROW(c2, 2) \
    DOTROW(c3, 3) DOTROW(c4, 4) DOTROW(c5, 5) \
    const f32x4 gv = GV; const f32x2 gn = GN; \
    const int tf = tl + 2 + (PR); \
    if (tf < CH) { \
      GV = *(const f32x4*)(rz + (size_t)tf * 256 + 4 * g); \
      GN = *(const f32x2*)(nb + (size_t)tf * 128 + 2 * g); \
    } \
    const float a0 = red8(c0.x + c0.y), a1 = red8(c1.x + c1.y); \
    const float a2 = red8(c2.x + c2.y), a3 = red8(c3.x + c3.y); \
    const float a4 = red8(c4.x + c4.y), a5 = red8(c5.x + c5.y); \
    const float r0 = sigm(gv.x + a0), z0 = sigm(gv.y + a2); \
    const float r1 = sigm(gv.z + a1), z1 = sigm(gv.w + a3); \
    const float n0 = tanh_fast(gn.x + r0 * (a4 + bhn0)); \
    const float n1 = tanh_fast(gn.y + r1 * (a5 + bhn1)); \
    hp0 = (1.f - z0) * n0 + z0 * hp0; \
    hp1 = (1.f - z1) * n1 + z1 * hp1; \
    if (cs == 0) { \
      f32x2 hw = {hp0, hp1}; \
      *(f32x2*)&hbuf[(PR) ^ 1][u0] = hw; \
      if (h0out) *(f32x2*)(h0out + (size_t)(tl + (PR)) * HDIM + u0) = hw; \
    } \
    __syncthreads(); \
  } while (0)

  for (int tl = 0; tl < CH; tl += 2) {
    RSTEP(0, gvA, gnA);
    RSTEP(1, gvB, gnB);
  }
#undef RSTEP
#undef DOTROW

  if (cs == 0) {
    f32x2 hw = {hp0, hp1};
    *(f32x2*)(hstate + u0) = hw;
    if (outp) *(f32x2*)(outp + u0) = hw;
  }
}

// ============== army phase A: gi0 = w_ih0 @ x + bias (x-only, chunk c) ==============
__device__ __forceinline__ void role_giA(int rb, int c, const float* __restrict__ x,
                                         const float* __restrict__ w_ih0,
                                         const float* __restrict__ b_ih0,
                                         const float* __restrict__ b_hh0,
                                         float* __restrict__ rz, float* __restrict__ nb) {
  const int tid = threadIdx.x;
  const int u = tid & 127, sb = tid >> 7;           // 4 step-batches of 256
  const int row = rb * 128 + u;
  const f32x4 wa = *(const f32x4*)(w_ih0 + (size_t)row * 8);
  const f32x4 wb = *(const f32x4*)(w_ih0 + (size_t)row * 8 + 4);
  const float bias = (rb < 2) ? (b_ih0[row] + b_hh0[row]) : b_ih0[row];
  const int m = u >> 1, sub = u & 1;
  for (int i = 0; i < CH / 4; ++i) {
    const int tl = sb * (CH / 4) + i;
    const float* xp = x + ((size_t)c * CH + tl) * 8;
    const f32x4 xa = *(const f32x4*)xp;
    const f32x4 xb2 = *(const f32x4*)(xp + 4);
    float acc = bias;   // bias-seeded sequential fmaf (r1-proven association)
    acc = fmaf(wa.x, xa.x, acc); acc = fmaf(wa.y, xa.y, acc);
    acc = fmaf(wa.z, xa.z, acc); acc = fmaf(wa.w, xa.w, acc);
    acc = fmaf(wb.x, xb2.x, acc); acc = fmaf(wb.y, xb2.y, acc);
    acc = fmaf(wb.z, xb2.z, acc); acc = fmaf(wb.w, xb2.w, acc);
    if (rb < 2) rz[(size_t)tl * 256 + 4 * m + 2 * sub + rb] = acc;
    else        nb[(size_t)tl * 128 + u] = acc;
  }
}

// ============== army phase B: gi1 = w_ih1 @ h0 + bias (chunk cb) ==============
__device__ __forceinline__ void role_giB(int rb, const float* __restrict__ h0src,
                                         const float* __restrict__ w_ih1,
                                         const float* __restrict__ b_ih1,
                                         const float* __restrict__ b_hh1,
                                         float* __restrict__ rz, float* __restrict__ nb) {
  __shared__ __align__(16) float hsg[2][GS * HDIM];   // 2 x 4KB h0 staging
  const int tid = threadIdx.x, cs = tid & 7, m = tid >> 3;
  const int R0 = rb * 128 + 2 * m, R1 = R0 + 1;
  f32x4 V0[4], V1[4];
  {
    const float* p0 = w_ih1 + (size_t)R0 * 128 + 8 * cs;
    const float* p1 = w_ih1 + (size_t)R1 * 128 + 8 * cs;
    V0[0] = *(const f32x4*)p0;        V0[1] = *(const f32x4*)(p0 + 4);
    V0[2] = *(const f32x4*)(p0 + 64); V0[3] = *(const f32x4*)(p0 + 68);
    V1[0] = *(const f32x4*)p1;        V1[1] = *(const f32x4*)(p1 + 4);
    V1[2] = *(const f32x4*)(p1 + 64); V1[3] = *(const f32x4*)(p1 + 68);
  }
  const float b0 = (rb < 2) ? (b_ih1[R0] + b_hh1[R0]) : b_ih1[R0];
  const float b1 = (rb < 2) ? (b_ih1[R1] + b_hh1[R1]) : b_ih1[R1];

  if (tid < 256) ((f32x4*)hsg[0])[tid] = ((const f32x4*)h0src)[tid];
  __syncthreads();
  int cur = 0;
  for (int gb = 0; gb < CH / GS; ++gb) {
    f32x4 pf;
    const bool hv = (gb + 1 < CH / GS) && (tid < 256);
    if (hv) pf = ((const f32x4*)(h0src + (size_t)(gb + 1) * (GS * HDIM)))[tid];
    #pragma unroll
    for (int s = 0; s < GS; ++s) {
      const float* hb = hsg[cur] + s * HDIM;
      const f32x4 hA = *(const f32x4*)(hb + 8 * cs);
      const f32x4 hB = *(const f32x4*)(hb + 8 * cs + 4);
      const f32x4 hC = *(const f32x4*)(hb + 64 + 8 * cs);
      const f32x4 hD = *(const f32x4*)(hb + 64 + 8 * cs + 4);
      f32x2 d0 = {0.f, 0.f}, d1 = d0;
      pkfma(d0, lo2(V0[0]), lo2(hA)); pkfma(d0, hi2(V0[0]), hi2(hA));
      pkfma(d0, lo2(V0[1]), lo2(hB)); pkfma(d0, hi2(V0[1]), hi2(hB));
      pkfma(d0, lo2(V0[2]), lo2(hC)); pkfma(d0, hi2(V0[2]), hi2(hC));
      pkfma(d0, lo2(V0[3]), lo2(hD)); pkfma(d0, hi2(V0[3]), hi2(hD));
      pkfma(d1, lo2(V1[0]), lo2(hA)); pkfma(d1, hi2(V1[0]), hi2(hA));
      pkfma(d1, lo2(V1[1]), lo2(hB)); pkfma(d1, hi2(V1[1]), hi2(hB));
      pkfma(d1, lo2(V1[2]), lo2(hC)); pkfma(d1, hi2(V1[2]), hi2(hC));
      pkfma(d1, lo2(V1[3]), lo2(hD)); pkfma(d1, hi2(V1[3]), hi2(hD));
      const float a0 = red8(d0.x + d0.y) + b0;
      const float a1 = red8(d1.x + d1.y) + b1;
      if (cs == 0) {
        const int tl = gb * GS + s;
        if (rb < 2) {
          rz[(size_t)tl * 256 + 4 * m + rb] = a0;
          rz[(size_t)tl * 256 + 4 * m + 2 + rb] = a1;
        } else {
          f32x2 nv = {a0, a1};
          *(f32x2*)(nb + (size_t)tl * 128 + 2 * m) = nv;
        }
      }
    }
    if (hv) ((f32x4*)hsg[cur ^ 1])[tid] = pf;
    __syncthreads();
    cur ^= 1;
  }
}

// =============== the pipelined kernel (5 blocks x 512 threads) ===============
__global__ __launch_bounds__(512)
void gru_pipe(const float* __restrict__ x, float* __restrict__ out,
              const float* __restrict__ w_ih0, const float* __restrict__ w_hh0,
              const float* __restrict__ b_ih0, const float* __restrict__ b_hh0,
              const float* __restrict__ w_ih1, const float* __restrict__ w_hh1,
              const float* __restrict__ b_ih1, const float* __restrict__ b_hh1,
              float* __restrict__ hstate0, float* __restrict__ hstate1,
              float* __restrict__ h0ring, float* __restrict__ gi0rz,
              float* __restrict__ gi0n, float* __restrict__ gi1rz,
              float* __restrict__ gi1n, int k) {
  // LDS pad: total ~56KB/block -> at most 2 blocks/CU. Cheapens the RA's
  // occupancy-vs-pressure tradeoff without attributes. Volatile write keeps it.
  __shared__ float ldspad[11776];
  if (threadIdx.x == 511) ((volatile float*)ldspad)[0] = (float)k;

  const int bid = blockIdx.x;
  if (bid == 0) {
    const int c = k - 1;
    if (c >= 0 && c < NC)
      rec_layer(w_hh0, b_hh0,
                gi0rz + (size_t)(c & 1) * CH * 256, gi0n + (size_t)(c & 1) * CH * 128,
                hstate0, h0ring + (size_t)(c & 1) * CH * HDIM, nullptr, c);
  } else if (bid == 1) {
    const int c = k - 3;
    if (c >= 0 && c < NC)
      rec_layer(w_hh1, b_hh1,
                gi1rz + (size_t)(c & 1) * CH * 256, gi1n + (size_t)(c & 1) * CH * 128,
                hstate1, nullptr, (c == NC - 1) ? out : nullptr, c);
  } else {
    const int rb = bid - 2;
    if (k < NC)
      role_giA(rb, k, x, w_ih0, b_ih0, b_hh0,
               gi0rz + (size_t)(k & 1) * CH * 256, gi0n + (size_t)(k & 1) * CH * 128);
    const int cb = k - 2;
    if (cb >= 0 && cb < NC)
      role_giB(rb, h0ring + (size_t)(cb & 1) * CH * HDIM, w_ih1, b_ih1, b_hh1,
               gi1rz + (size_t)(cb & 1) * CH * 256, gi1n + (size_t)(cb & 1) * CH * 128);
  }
}

extern "C" void kernel_launch(void* const* d_in, const int* in_sizes, int n_in,
                              void* d_out, int out_size, void* d_ws, size_t ws_size,
                              hipStream_t stream) {
  (void)in_sizes; (void)n_in; (void)out_size; (void)ws_size;
  const float* x     = (const float*)d_in[0];
  const float* w_ih0 = (const float*)d_in[1];
  const float* w_hh0 = (const float*)d_in[2];
  const float* b_ih0 = (const float*)d_in[3];
  const float* b_hh0 = (const float*)d_in[4];
  const float* w_ih1 = (const float*)d_in[5];
  const float* w_hh1 = (const float*)d_in[6];
  const float* b_ih1 = (const float*)d_in[7];
  const float* b_hh1 = (const float*)d_in[8];
  float* out = (float*)d_out;

  float* p = (float*)d_ws;
  float* hstate0 = p; p += 128;
  float* hstate1 = p; p += 128;
  float* h0ring  = p; p += (size_t)2 * CH * 128;
  float* gi0rz   = p; p += (size_t)2 * CH * 256;
  float* gi0n    = p; p += (size_t)2 * CH * 128;
  float* gi1rz   = p; p += (size_t)2 * CH * 256;
  float* gi1n    = p; p += (size_t)2 * CH * 128;   // total ~7.3 MB

  for (int k = 0; k <= NC + 2; ++k) {
    hipLaunchKernelGGL(gru_pipe, dim3(5), dim3(512), 0, stream,
                       x, out, w_ih0, w_hh0, b_ih0, b_hh0,
                       w_ih1, w_hh1, b_ih1, b_hh1,
                       hstate0, hstate1, h0ring, gi0rz, gi0n, gi1rz, gi1n, k);
  }
}

// Round 13
// 19657.581 us; speedup vs baseline: 1.4505x; 1.4505x over previous
//
#include <hip/hip_runtime.h>

// 2-layer GRU, I=8, H=128, T=32768 steps, out = final h1 (128 f32).
// Launch-level pipeline (proven r7-r11). Launch k, disjoint blocks:
//   blocks 2-4 (army): A: gi0 = w_ih0@x + b, chunk k (x-only, ahead)
//                      B: gi1 = w_ih1@h0 + b, chunk k-2
//   block 0 (l0): layer-0 recurrence, chunk k-1 (consumes gi0, publishes h0)
//   block 1 (l1): layer-1 recurrence, chunk k-3 (consumes gi1, writes out)
//
// r12 post-mortem: NaN from missing CDNA trans-op wait states — v_exp/v_rcp
// results were consumed by the NEXT instruction (no hw interlock for trans
// forwarding). Fix: interleaved two-unit GATES macro, every trans result
// consumed >=2 instructions later. All else identical to r12's structure
// (whole recurrence loop = one asm block, weights hard-pinned in v100-195;
// the allocator cannot spill inside asm -> residency is structural).

#define T_STEPS 32768
#define HDIM 128
#define CH 1024
#define NC (T_STEPS / CH)
#define GS 8

typedef __attribute__((ext_vector_type(2))) float f32x2;
typedef __attribute__((ext_vector_type(4))) float f32x4;

__device__ __forceinline__ f32x2 lo2(f32x4 v) { return __builtin_shufflevector(v, v, 0, 1); }
__device__ __forceinline__ f32x2 hi2(f32x4 v) { return __builtin_shufflevector(v, v, 2, 3); }
__device__ __forceinline__ void pkfma(f32x2& acc, f32x2 a, f32x2 b) {
  asm("v_pk_fma_f32 %0, %1, %2, %0" : "+v"(acc) : "v"(a), "v"(b));
}
__device__ __forceinline__ float red8(float v) {
  int t = __builtin_amdgcn_mov_dpp(__builtin_bit_cast(int, v), 0xB1, 0xF, 0xF, true);
  v += __builtin_bit_cast(float, t);
  t = __builtin_amdgcn_mov_dpp(__builtin_bit_cast(int, v), 0x4E, 0xF, 0xF, true);
  v += __builtin_bit_cast(float, t);
  t = __builtin_amdgcn_mov_dpp(__builtin_bit_cast(int, v), 0x141, 0xF, 0xF, true);
  v += __builtin_bit_cast(float, t);
  return v;
}

// ---------------- asm building blocks for the recurrence ----------------
#define PKM(D, A, B) "v_pk_mul_f32 v[" D "], v[" A "], v[" B "]\n\t"
#define PKF(D, A, B) "v_pk_fma_f32 v[" D "], v[" A "], v[" B "], v[" D "]\n\t"

#define DOTROW(ACC, W0, W1, W2, W3, W4, W5, W6, W7) \
  PKM(ACC, W0, "60:61") PKF(ACC, W1, "62:63") \
  PKF(ACC, W2, "64:65") PKF(ACC, W3, "66:67") \
  PKF(ACC, W4, "68:69") PKF(ACC, W5, "70:71") \
  PKF(ACC, W6, "72:73") PKF(ACC, W7, "74:75")

#define DOTS6 \
  DOTROW("76:77","100:101","102:103","104:105","106:107","108:109","110:111","112:113","114:115") \
  DOTROW("78:79","116:117","118:119","120:121","122:123","124:125","126:127","128:129","130:131") \
  DOTROW("80:81","132:133","134:135","136:137","138:139","140:141","142:143","144:145","146:147") \
  DOTROW("82:83","148:149","150:151","152:153","154:155","156:157","158:159","160:161","162:163") \
  DOTROW("84:85","164:165","166:167","168:169","170:171","172:173","174:175","176:177","178:179") \
  DOTROW("86:87","180:181","182:183","184:185","186:187","188:189","190:191","192:193","194:195")

// stage-interleaved across the 6 sums: >=5 insts between any DPP def and use
// (covers the documented 2-wait-state VALU-write -> DPP-read hazard)
#define RED6 \
  "v_add_f32 v50, v76, v77\n\t" "v_add_f32 v51, v78, v79\n\t" \
  "v_add_f32 v52, v80, v81\n\t" "v_add_f32 v53, v82, v83\n\t" \
  "v_add_f32 v54, v84, v85\n\t" "v_add_f32 v55, v86, v87\n\t" \
  "v_add_f32 v50, v50, v50 quad_perm:[1,0,3,2]\n\t" \
  "v_add_f32 v51, v51, v51 quad_perm:[1,0,3,2]\n\t" \
  "v_add_f32 v52, v52, v52 quad_perm:[1,0,3,2]\n\t" \
  "v_add_f32 v53, v53, v53 quad_perm:[1,0,3,2]\n\t" \
  "v_add_f32 v54, v54, v54 quad_perm:[1,0,3,2]\n\t" \
  "v_add_f32 v55, v55, v55 quad_perm:[1,0,3,2]\n\t" \
  "v_add_f32 v50, v50, v50 quad_perm:[2,3,0,1]\n\t" \
  "v_add_f32 v51, v51, v51 quad_perm:[2,3,0,1]\n\t" \
  "v_add_f32 v52, v52, v52 quad_perm:[2,3,0,1]\n\t" \
  "v_add_f32 v53, v53, v53 quad_perm:[2,3,0,1]\n\t" \
  "v_add_f32 v54, v54, v54 quad_perm:[2,3,0,1]\n\t" \
  "v_add_f32 v55, v55, v55 quad_perm:[2,3,0,1]\n\t" \
  "v_add_f32 v50, v50, v50 row_half_mirror\n\t" \
  "v_add_f32 v51, v51, v51 row_half_mirror\n\t" \
  "v_add_f32 v52, v52, v52 row_half_mirror\n\t" \
  "v_add_f32 v53, v53, v53 row_half_mirror\n\t" \
  "v_add_f32 v54, v54, v54 row_half_mirror\n\t" \
  "v_add_f32 v55, v55, v55 row_half_mirror\n\t"

// Both units interleaved; every v_exp/v_rcp result consumed >=2 insts later.
// sigm(x)=rcp(1+exp2(-x*log2e)); tanh(y)=fma(-2, rcp(1+exp2(y*2log2e)), 1).
// a-values: v50=a_r0 v51=a_r1 v52=a_z0 v53=a_z1 v54=a_n0 v55=a_n1; h=v48,v49.
#define GATES(R0, Z0, R1, Z1, N0, N1) \
  "v_add_f32 v56, " R0 ", v50\n\t" \
  "v_add_f32 v57, " R1 ", v51\n\t" \
  "v_add_f32 v58, " Z0 ", v52\n\t" \
  "v_add_f32 v59, " Z1 ", v53\n\t" \
  "v_mul_f32 v56, 0xbfb8aa3b, v56\n\t" \
  "v_mul_f32 v57, 0xbfb8aa3b, v57\n\t" \
  "v_mul_f32 v58, 0xbfb8aa3b, v58\n\t" \
  "v_mul_f32 v59, 0xbfb8aa3b, v59\n\t" \
  "v_exp_f32 v56, v56\n\t" \
  "v_exp_f32 v57, v57\n\t" \
  "v_exp_f32 v58, v58\n\t" \
  "v_exp_f32 v59, v59\n\t" \
  "v_add_f32 v56, 1.0, v56\n\t" \
  "v_add_f32 v57, 1.0, v57\n\t" \
  "v_add_f32 v58, 1.0, v58\n\t" \
  "v_add_f32 v59, 1.0, v59\n\t" \
  "v_rcp_f32 v56, v56\n\t" \
  "v_rcp_f32 v57, v57\n\t" \
  "v_rcp_f32 v58, v58\n\t" \
  "v_rcp_f32 v59, v59\n\t" \
  "v_add_f32 v50, %[bh0], v54\n\t" \
  "v_add_f32 v51, %[bh1], v55\n\t" \
  "v_fma_f32 v50, v56, v50, " N0 "\n\t" \
  "v_fma_f32 v51, v57, v51, " N1 "\n\t" \
  "v_mul_f32 v50, 0x4038aa3b, v50\n\t" \
  "v_mul_f32 v51, 0x4038aa3b, v51\n\t" \
  "v_exp_f32 v50, v50\n\t" \
  "v_exp_f32 v51, v51\n\t" \
  "s_nop 0\n\t" \
  "v_add_f32 v50, 1.0, v50\n\t" \
  "v_add_f32 v51, 1.0, v51\n\t" \
  "v_rcp_f32 v50, v50\n\t" \
  "v_rcp_f32 v51, v51\n\t" \
  "s_nop 0\n\t" \
  "v_fma_f32 v50, -2.0, v50, 1.0\n\t" \
  "v_fma_f32 v51, -2.0, v51, 1.0\n\t" \
  "v_sub_f32 v52, v48, v50\n\t" \
  "v_sub_f32 v53, v49, v51\n\t" \
  "v_fma_f32 v48, v58, v52, v50\n\t" \
  "v_fma_f32 v49, v59, v53, v51\n\t"

// =============== recurrence (l0 and l1: identical machine) ===============
// Thread: cs=tid&7 (cols [8cs,8cs+8) and [64+8cs,..)); g=tid>>3 (units 2g,2g+1).
// Rows in v100-195: u0r, u1r, u0z, u1z, u0n, u1n (16 regs each).
__device__ __forceinline__ void rec_asm(const float* __restrict__ Whh,
                                        const float* __restrict__ bhh,
                                        const float* __restrict__ rz,
                                        const float* __restrict__ nb,
                                        float* __restrict__ hstate,
                                        float* __restrict__ h0out,
                                        float* __restrict__ outp, int c) {
  __shared__ __align__(16) float hbuf[2][HDIM];
  const int tid = threadIdx.x, cs = tid & 7, g = tid >> 3;
  const int u0 = 2 * g;
  float hp0 = 0.f, hp1 = 0.f;
  if (c > 0) { hp0 = hstate[u0]; hp1 = hstate[u0 + 1]; }
  const float bh0 = bhh[256 + u0], bh1 = bhh[257 + u0];
  unsigned vow  = (unsigned)(u0 * 512 + 32 * cs);   // weight row base (bytes)
  unsigned vow1 = vow + 65536u;                     // +128 rows
  unsigned vow2 = vow + 131072u;                    // +256 rows
  unsigned vorz = (unsigned)(2048 + 16 * g);        // rz stream at t=2
  unsigned vonb = (unsigned)(1024 + 8 * g);         // nb stream at t=2
  unsigned voho = (unsigned)(8 * g);                // h-out at t=0
  unsigned pa = (unsigned)(size_t)&hbuf[0][8 * cs]; // LDS read base (parity A)
  unsigned pw = (unsigned)(size_t)&hbuf[0][u0];     // LDS write base
  int cnt = CH / 2;

  asm volatile(
    // ---------- preamble: 24 weight loads into v100-195 ----------
    "global_load_dwordx4 v[100:103], %[vow], %[wb]\n\t"
    "global_load_dwordx4 v[104:107], %[vow], %[wb] offset:16\n\t"
    "global_load_dwordx4 v[108:111], %[vow], %[wb] offset:256\n\t"
    "global_load_dwordx4 v[112:115], %[vow], %[wb] offset:272\n\t"
    "global_load_dwordx4 v[116:119], %[vow], %[wb] offset:512\n\t"
    "global_load_dwordx4 v[120:123], %[vow], %[wb] offset:528\n\t"
    "global_load_dwordx4 v[124:127], %[vow], %[wb] offset:768\n\t"
    "global_load_dwordx4 v[128:131], %[vow], %[wb] offset:784\n\t"
    "global_load_dwordx4 v[132:135], %[vow1], %[wb]\n\t"
    "global_load_dwordx4 v[136:139], %[vow1], %[wb] offset:16\n\t"
    "global_load_dwordx4 v[140:143], %[vow1], %[wb] offset:256\n\t"
    "global_load_dwordx4 v[144:147], %[vow1], %[wb] offset:272\n\t"
    "global_load_dwordx4 v[148:151], %[vow1], %[wb] offset:512\n\t"
    "global_load_dwordx4 v[152:155], %[vow1], %[wb] offset:528\n\t"
    "global_load_dwordx4 v[156:159], %[vow1], %[wb] offset:768\n\t"
    "global_load_dwordx4 v[160:163], %[vow1], %[wb] offset:784\n\t"
    "global_load_dwordx4 v[164:167], %[vow2], %[wb]\n\t"
    "global_load_dwordx4 v[168:171], %[vow2], %[wb] offset:16\n\t"
    "global_load_dwordx4 v[172:175], %[vow2], %[wb] offset:256\n\t"
    "global_load_dwordx4 v[176:179], %[vow2], %[wb] offset:272\n\t"
    "global_load_dwordx4 v[180:183], %[vow2], %[wb] offset:512\n\t"
    "global_load_dwordx4 v[184:187], %[vow2], %[wb] offset:528\n\t"
    "global_load_dwordx4 v[188:191], %[vow2], %[wb] offset:768\n\t"
    "global_load_dwordx4 v[192:195], %[vow2], %[wb] offset:784\n\t"
    // ---------- preamble: gates(0) -> A slots, gates(1) -> B slots ----------
    "global_load_dwordx4 v[88:91], %[vorz], %[rzb] offset:-2048\n\t"
    "global_load_dwordx2 v[92:93], %[vonb], %[nbb] offset:-1024\n\t"
    "global_load_dwordx4 v[94:97], %[vorz], %[rzb] offset:-1024\n\t"
    "global_load_dwordx2 v[98:99], %[vonb], %[nbb] offset:-512\n\t"
    // ---------- h(0) into LDS buf0 ----------
    "v_mov_b32 v48, %[h0]\n\t"
    "v_mov_b32 v49, %[h1]\n\t"
    "ds_write_b64 %[pw], v[48:49]\n\t"
    "s_waitcnt vmcnt(0) lgkmcnt(0)\n\t"
    "s_barrier\n\t"
    "Lrec%=:\n\t"
    // ================= phase A (even t): h in buf0 =================
    "ds_read_b128 v[60:63], %[pa]\n\t"
    "ds_read_b128 v[64:67], %[pa] offset:16\n\t"
    "ds_read_b128 v[68:71], %[pa] offset:256\n\t"
    "ds_read_b128 v[72:75], %[pa] offset:272\n\t"
    "s_waitcnt lgkmcnt(0)\n\t"
    DOTS6
    RED6
    "s_waitcnt vmcnt(4)\n\t"
    GATES("v88", "v89", "v90", "v91", "v92", "v93")
    "global_load_dwordx4 v[88:91], %[vorz], %[rzb]\n\t"
    "global_load_dwordx2 v[92:93], %[vonb], %[nbb]\n\t"
    "ds_write_b64 %[pw], v[48:49] offset:512\n\t"
    "global_store_dwordx2 %[voho], v[48:49], %[hob]\n\t"
    "s_waitcnt lgkmcnt(0)\n\t"
    "s_barrier\n\t"
    // ================= phase B (odd t): h in buf1 =================
    "ds_read_b128 v[60:63], %[pa] offset:512\n\t"
    "ds_read_b128 v[64:67], %[pa] offset:528\n\t"
    "ds_read_b128 v[68:71], %[pa] offset:768\n\t"
    "ds_read_b128 v[72:75], %[pa] offset:784\n\t"
    "s_waitcnt lgkmcnt(0)\n\t"
    DOTS6
    RED6
    "s_waitcnt vmcnt(4)\n\t"
    GATES("v94", "v95", "v96", "v97", "v98", "v99")
    "global_load_dwordx4 v[94:97], %[vorz], %[rzb] offset:1024\n\t"
    "global_load_dwordx2 v[98:99], %[vonb], %[nbb] offset:512\n\t"
    "ds_write_b64 %[pw], v[48:49]\n\t"
    "global_store_dwordx2 %[voho], v[48:49], %[hob] offset:512\n\t"
    "v_add_u32 %[vorz], 2048, %[vorz]\n\t"
    "v_add_u32 %[vonb], 1024, %[vonb]\n\t"
    "v_add_u32 %[voho], 1024, %[voho]\n\t"
    "s_waitcnt lgkmcnt(0)\n\t"
    "s_barrier\n\t"
    "s_sub_u32 %[cnt], %[cnt], 1\n\t"
    "s_cmp_lg_u32 %[cnt], 0\n\t"
    "s_cbranch_scc1 Lrec%=\n\t"
    "v_mov_b32 %[h0], v48\n\t"
    "v_mov_b32 %[h1], v49\n\t"
    : [vorz]"+v"(vorz), [vonb]"+v"(vonb), [voho]"+v"(voho), [cnt]"+s"(cnt),
      [h0]"+v"(hp0), [h1]"+v"(hp1)
    : [wb]"s"(Whh), [rzb]"s"(rz), [nbb]"s"(nb), [hob]"s"(h0out),
      [vow]"v"(vow), [vow1]"v"(vow1), [vow2]"v"(vow2),
      [pa]"v"(pa), [pw]"v"(pw), [bh0]"v"(bh0), [bh1]"v"(bh1)
    : "memory", "scc",
      "v48","v49","v50","v51","v52","v53","v54","v55","v56","v57","v58","v59",
      "v60","v61","v62","v63","v64","v65","v66","v67","v68","v69","v70","v71",
      "v72","v73","v74","v75","v76","v77","v78","v79","v80","v81","v82","v83",
      "v84","v85","v86","v87","v88","v89","v90","v91","v92","v93","v94","v95",
      "v96","v97","v98","v99","v100","v101","v102","v103","v104","v105","v106",
      "v107","v108","v109","v110","v111","v112","v113","v114","v115","v116",
      "v117","v118","v119","v120","v121","v122","v123","v124","v125","v126",
      "v127","v128","v129","v130","v131","v132","v133","v134","v135","v136",
      "v137","v138","v139","v140","v141","v142","v143","v144","v145","v146",
      "v147","v148","v149","v150","v151","v152","v153","v154","v155","v156",
      "v157","v158","v159","v160","v161","v162","v163","v164","v165","v166",
      "v167","v168","v169","v170","v171","v172","v173","v174","v175","v176",
      "v177","v178","v179","v180","v181","v182","v183","v184","v185","v186",
      "v187","v188","v189","v190","v191","v192","v193","v194","v195");

  if (cs == 0) {
    hstate[u0] = hp0; hstate[u0 + 1] = hp1;
    if (outp) { outp[u0] = hp0; outp[u0 + 1] = hp1; }
  }
}

// ============== army phase A: gi0 = w_ih0 @ x + bias (r11-proven) ==============
__device__ __forceinline__ void role_giA(int rb, int c, const float* __restrict__ x,
                                         const float* __restrict__ w_ih0,
                                         const float* __restrict__ b_ih0,
                                         const float* __restrict__ b_hh0,
                                         float* __restrict__ rz, float* __restrict__ nb) {
  const int tid = threadIdx.x;
  const int u = tid & 127, sb = tid >> 7;
  const int row = rb * 128 + u;
  const f32x4 wa = *(const f32x4*)(w_ih0 + (size_t)row * 8);
  const f32x4 wb = *(const f32x4*)(w_ih0 + (size_t)row * 8 + 4);
  const float bias = (rb < 2) ? (b_ih0[row] + b_hh0[row]) : b_ih0[row];
  const int m = u >> 1, sub = u & 1;
  for (int i = 0; i < CH / 4; ++i) {
    const int tl = sb * (CH / 4) + i;
    const float* xp = x + ((size_t)c * CH + tl) * 8;
    const f32x4 xa = *(const f32x4*)xp;
    const f32x4 xb2 = *(const f32x4*)(xp + 4);
    float acc = bias;
    acc = fmaf(wa.x, xa.x, acc); acc = fmaf(wa.y, xa.y, acc);
    acc = fmaf(wa.z, xa.z, acc); acc = fmaf(wa.w, xa.w, acc);
    acc = fmaf(wb.x, xb2.x, acc); acc = fmaf(wb.y, xb2.y, acc);
    acc = fmaf(wb.z, xb2.z, acc); acc = fmaf(wb.w, xb2.w, acc);
    if (rb < 2) rz[(size_t)tl * 256 + 4 * m + 2 * sub + rb] = acc;
    else        nb[(size_t)tl * 128 + u] = acc;
  }
}

// ============== army phase B: gi1 = w_ih1 @ h0 + bias (r11-proven) ==============
__device__ __forceinline__ void role_giB(int rb, const float* __restrict__ h0src,
                                         const float* __restrict__ w_ih1,
                                         const float* __restrict__ b_ih1,
                                         const float* __restrict__ b_hh1,
                                         float* __restrict__ rz, float* __restrict__ nb) {
  __shared__ __align__(16) float hsg[2][GS * HDIM];
  const int tid = threadIdx.x, cs = tid & 7, m = tid >> 3;
  const int R0 = rb * 128 + 2 * m, R1 = R0 + 1;
  f32x4 V0[4], V1[4];
  {
    const float* p0 = w_ih1 + (size_t)R0 * 128 + 8 * cs;
    const float* p1 = w_ih1 + (size_t)R1 * 128 + 8 * cs;
    V0[0] = *(const f32x4*)p0;        V0[1] = *(const f32x4*)(p0 + 4);
    V0[2] = *(const f32x4*)(p0 + 64); V0[3] = *(const f32x4*)(p0 + 68);
    V1[0] = *(const f32x4*)p1;        V1[1] = *(const f32x4*)(p1 + 4);
    V1[2] = *(const f32x4*)(p1 + 64); V1[3] = *(const f32x4*)(p1 + 68);
  }
  const float b0 = (rb < 2) ? (b_ih1[R0] + b_hh1[R0]) : b_ih1[R0];
  const float b1 = (rb < 2) ? (b_ih1[R1] + b_hh1[R1]) : b_ih1[R1];

  if (tid < 256) ((f32x4*)hsg[0])[tid] = ((const f32x4*)h0src)[tid];
  __syncthreads();
  int cur = 0;
  for (int gb = 0; gb < CH / GS; ++gb) {
    f32x4 pf;
    const bool hv = (gb + 1 < CH / GS) && (tid < 256);
    if (hv) pf = ((const f32x4*)(h0src + (size_t)(gb + 1) * (GS * HDIM)))[tid];
    #pragma unroll
    for (int s = 0; s < GS; ++s) {
      const float* hb = hsg[cur] + s * HDIM;
      const f32x4 hA = *(const f32x4*)(hb + 8 * cs);
      const f32x4 hB = *(const f32x4*)(hb + 8 * cs + 4);
      const f32x4 hC = *(const f32x4*)(hb + 64 + 8 * cs);
      const f32x4 hD = *(const f32x4*)(hb + 64 + 8 * cs + 4);
      f32x2 d0 = {0.f, 0.f}, d1 = d0;
      pkfma(d0, lo2(V0[0]), lo2(hA)); pkfma(d0, hi2(V0[0]), hi2(hA));
      pkfma(d0, lo2(V0[1]), lo2(hB)); pkfma(d0, hi2(V0[1]), hi2(hB));
      pkfma(d0, lo2(V0[2]), lo2(hC)); pkfma(d0, hi2(V0[2]), hi2(hC));
      pkfma(d0, lo2(V0[3]), lo2(hD)); pkfma(d0, hi2(V0[3]), hi2(hD));
      pkfma(d1, lo2(V1[0]), lo2(hA)); pkfma(d1, hi2(V1[0]), hi2(hA));
      pkfma(d1, lo2(V1[1]), lo2(hB)); pkfma(d1, hi2(V1[1]), hi2(hB));
      pkfma(d1, lo2(V1[2]), lo2(hC)); pkfma(d1, hi2(V1[2]), hi2(hC));
      pkfma(d1, lo2(V1[3]), lo2(hD)); pkfma(d1, hi2(V1[3]), hi2(hD));
      const float a0 = red8(d0.x + d0.y) + b0;
      const float a1 = red8(d1.x + d1.y) + b1;
      if (cs == 0) {
        const int tl = gb * GS + s;
        if (rb < 2) {
          rz[(size_t)tl * 256 + 4 * m + rb] = a0;
          rz[(size_t)tl * 256 + 4 * m + 2 + rb] = a1;
        } else {
          f32x2 nv = {a0, a1};
          *(f32x2*)(nb + (size_t)tl * 128 + 2 * m) = nv;
        }
      }
    }
    if (hv) ((f32x4*)hsg[cur ^ 1])[tid] = pf;
    __syncthreads();
    cur ^= 1;
  }
}

// =============== the pipelined kernel (5 blocks x 512 threads) ===============
__global__ __launch_bounds__(512)
void gru_pipe(const float* __restrict__ x, float* __restrict__ out,
              const float* __restrict__ w_ih0, const float* __restrict__ w_hh0,
              const float* __restrict__ b_ih0, const float* __restrict__ b_hh0,
              const float* __restrict__ w_ih1, const float* __restrict__ w_hh1,
              const float* __restrict__ b_ih1, const float* __restrict__ b_hh1,
              float* __restrict__ hstate0, float* __restrict__ hstate1,
              float* __restrict__ h0ring, float* __restrict__ gi0rz,
              float* __restrict__ gi0n, float* __restrict__ gi1rz,
              float* __restrict__ gi1n, float* __restrict__ h1dump, int k) {
  const int bid = blockIdx.x;
  if (bid == 0) {
    const int c = k - 1;
    if (c >= 0 && c < NC)
      rec_asm(w_hh0, b_hh0,
              gi0rz + (size_t)(c & 1) * CH * 256, gi0n + (size_t)(c & 1) * CH * 128,
              hstate0, h0ring + (size_t)(c & 1) * CH * HDIM, nullptr, c);
  } else if (bid == 1) {
    const int c = k - 3;
    if (c >= 0 && c < NC)
      rec_asm(w_hh1, b_hh1,
              gi1rz + (size_t)(c & 1) * CH * 256, gi1n + (size_t)(c & 1) * CH * 128,
              hstate1, h1dump, (c == NC - 1) ? out : nullptr, c);
  } else {
    const int rb = bid - 2;
    if (k < NC)
      role_giA(rb, k, x, w_ih0, b_ih0, b_hh0,
               gi0rz + (size_t)(k & 1) * CH * 256, gi0n + (size_t)(k & 1) * CH * 128);
    const int cb = k - 2;
    if (cb >= 0 && cb < NC)
      role_giB(rb, h0ring + (size_t)(cb & 1) * CH * HDIM, w_ih1, b_ih1, b_hh1,
               gi1rz + (size_t)(cb & 1) * CH * 256, gi1n + (size_t)(cb & 1) * CH * 128);
  }
}

extern "C" void kernel_launch(void* const* d_in, const int* in_sizes, int n_in,
                              void* d_out, int out_size, void* d_ws, size_t ws_size,
                              hipStream_t stream) {
  (void)in_sizes; (void)n_in; (void)out_size; (void)ws_size;
  const float* x     = (const float*)d_in[0];
  const float* w_ih0 = (const float*)d_in[1];
  const float* w_hh0 = (const float*)d_in[2];
  const float* b_ih0 = (const float*)d_in[3];
  const float* b_hh0 = (const float*)d_in[4];
  const float* w_ih1 = (const float*)d_in[5];
  const float* w_hh1 = (const float*)d_in[6];
  const float* b_ih1 = (const float*)d_in[7];
  const float* b_hh1 = (const float*)d_in[8];
  float* out = (float*)d_out;

  float* p = (float*)d_ws;
  float* hstate0 = p; p += 128;
  float* hstate1 = p; p += 128;
  float* h0ring  = p; p += (size_t)2 * CH * 128;
  float* gi0rz   = p; p += (size_t)2 * CH * 256;
  float* gi0n    = p; p += (size_t)2 * CH * 128;
  float* gi1rz   = p; p += (size_t)2 * CH * 256;
  float* gi1n    = p; p += (size_t)2 * CH * 128;
  float* h1dump  = p; p += (size_t)CH * 128;       // l1 h-store sink (unread)

  for (int k = 0; k <= NC + 2; ++k) {
    hipLaunchKernelGGL(gru_pipe, dim3(5), dim3(512), 0, stream,
                       x, out, w_ih0, w_hh0, b_ih0, b_hh0,
                       w_ih1, w_hh1, b_ih1, b_hh1,
                       hstate0, hstate1, h0ring, gi0rz, gi0n, gi1rz, gi1n,
                       h1dump, k);
  }
}

// Round 14
// 19509.386 us; speedup vs baseline: 1.4615x; 1.0076x over previous
//
#include <hip/hip_runtime.h>

// 2-layer GRU, I=8, H=128, T=32768 steps, out = final h1 (128 f32).
// Launch-level pipeline (proven r7-r13). Launch k, disjoint blocks:
//   blocks 2-4 (army): A: gi0 = Wi0s@x + bA0, chunk k (x-only, ahead)
//                      B: gi1 = Wi1s@h0 + bA1, chunk k-2
//   block 0 (l0): layer-0 recurrence, chunk k-1 (consumes gi0, publishes h0)
//   block 1 (l1): layer-1 recurrence, chunk k-3 (consumes gi1, writes out)
// Recurrence loop = one asm block, weights hard-pinned v100-195 (r13-proven:
// 590us/launch, absmax 0.0). r14 surgical changes:
//  (1) conflict-free h ds_write: non-writer lanes (cs!=0) write to per-lane
//      dummy LDS (8-way same-address write serialization was on the critical
//      path every step, inside the lgkmcnt(0)+barrier).
//  (2) prep kernel pre-scales weights/biases (r,z rows * -log2e; n rows *
//      +2log2e, matching r13's working gate constants) -> GATES drops 6 muls
//      and each trans chain shortens by one op.

#define T_STEPS 32768
#define HDIM 128
#define CH 1024
#define NC (T_STEPS / CH)
#define GS 8

typedef __attribute__((ext_vector_type(2))) float f32x2;
typedef __attribute__((ext_vector_type(4))) float f32x4;

__device__ __forceinline__ f32x2 lo2(f32x4 v) { return __builtin_shufflevector(v, v, 0, 1); }
__device__ __forceinline__ f32x2 hi2(f32x4 v) { return __builtin_shufflevector(v, v, 2, 3); }
__device__ __forceinline__ void pkfma(f32x2& acc, f32x2 a, f32x2 b) {
  asm("v_pk_fma_f32 %0, %1, %2, %0" : "+v"(acc) : "v"(a), "v"(b));
}
__device__ __forceinline__ float red8(float v) {
  int t = __builtin_amdgcn_mov_dpp(__builtin_bit_cast(int, v), 0xB1, 0xF, 0xF, true);
  v += __builtin_bit_cast(float, t);
  t = __builtin_amdgcn_mov_dpp(__builtin_bit_cast(int, v), 0x4E, 0xF, 0xF, true);
  v += __builtin_bit_cast(float, t);
  t = __builtin_amdgcn_mov_dpp(__builtin_bit_cast(int, v), 0x141, 0xF, 0xF, true);
  v += __builtin_bit_cast(float, t);
  return v;
}

// =============== prep: scaled weight/bias copies into ws ===============
// r,z rows scaled by -log2(e) (gate = rcp(1+exp2(s))); n rows by +2*log2(e)
// (tanh(y) = fma(-2, rcp(1+exp2(2*log2e*y)), 1)) — signs match r13's
// verified 0xbfb8aa3b / 0x4038aa3b constants.
__global__ __launch_bounds__(256)
void gru_prep(const float* __restrict__ w_ih0, const float* __restrict__ w_hh0,
              const float* __restrict__ b_ih0, const float* __restrict__ b_hh0,
              const float* __restrict__ w_ih1, const float* __restrict__ w_hh1,
              const float* __restrict__ b_ih1, const float* __restrict__ b_hh1,
              float* __restrict__ W0s, float* __restrict__ W1s,
              float* __restrict__ Wi0s, float* __restrict__ Wi1s,
              float* __restrict__ bA0, float* __restrict__ bA1,
              float* __restrict__ bhnS0, float* __restrict__ bhnS1) {
  const float SRZ = -1.4426950408889634f;   // -log2(e)
  const float SN  =  2.8853900817779268f;   // +2*log2(e)
  const int i = blockIdx.x * 256 + threadIdx.x;
  if (i < 49152) {
    const float s = ((i >> 7) < 256) ? SRZ : SN;
    W0s[i]  = w_hh0[i] * s;
    W1s[i]  = w_hh1[i] * s;
    Wi1s[i] = w_ih1[i] * s;
  }
  if (i < 3072) Wi0s[i] = w_ih0[i] * (((i >> 3) < 256) ? SRZ : SN);
  if (i < 384) {
    bA0[i] = (i < 256) ? SRZ * (b_ih0[i] + b_hh0[i]) : SN * b_ih0[i];
    bA1[i] = (i < 256) ? SRZ * (b_ih1[i] + b_hh1[i]) : SN * b_ih1[i];
  }
  if (i < 128) {
    bhnS0[i] = SN * b_hh0[256 + i];
    bhnS1[i] = SN * b_hh1[256 + i];
  }
}

// ---------------- asm building blocks for the recurrence ----------------
#define PKM(D, A, B) "v_pk_mul_f32 v[" D "], v[" A "], v[" B "]\n\t"
#define PKF(D, A, B) "v_pk_fma_f32 v[" D "], v[" A "], v[" B "], v[" D "]\n\t"

#define DOTROW(ACC, W0, W1, W2, W3, W4, W5, W6, W7) \
  PKM(ACC, W0, "60:61") PKF(ACC, W1, "62:63") \
  PKF(ACC, W2, "64:65") PKF(ACC, W3, "66:67") \
  PKF(ACC, W4, "68:69") PKF(ACC, W5, "70:71") \
  PKF(ACC, W6, "72:73") PKF(ACC, W7, "74:75")

#define DOTS6 \
  DOTROW("76:77","100:101","102:103","104:105","106:107","108:109","110:111","112:113","114:115") \
  DOTROW("78:79","116:117","118:119","120:121","122:123","124:125","126:127","128:129","130:131") \
  DOTROW("80:81","132:133","134:135","136:137","138:139","140:141","142:143","144:145","146:147") \
  DOTROW("82:83","148:149","150:151","152:153","154:155","156:157","158:159","160:161","162:163") \
  DOTROW("84:85","164:165","166:167","168:169","170:171","172:173","174:175","176:177","178:179") \
  DOTROW("86:87","180:181","182:183","184:185","186:187","188:189","190:191","192:193","194:195")

// stage-interleaved across the 6 sums: >=5 insts between any DPP def and use
#define RED6 \
  "v_add_f32 v50, v76, v77\n\t" "v_add_f32 v51, v78, v79\n\t" \
  "v_add_f32 v52, v80, v81\n\t" "v_add_f32 v53, v82, v83\n\t" \
  "v_add_f32 v54, v84, v85\n\t" "v_add_f32 v55, v86, v87\n\t" \
  "v_add_f32 v50, v50, v50 quad_perm:[1,0,3,2]\n\t" \
  "v_add_f32 v51, v51, v51 quad_perm:[1,0,3,2]\n\t" \
  "v_add_f32 v52, v52, v52 quad_perm:[1,0,3,2]\n\t" \
  "v_add_f32 v53, v53, v53 quad_perm:[1,0,3,2]\n\t" \
  "v_add_f32 v54, v54, v54 quad_perm:[1,0,3,2]\n\t" \
  "v_add_f32 v55, v55, v55 quad_perm:[1,0,3,2]\n\t" \
  "v_add_f32 v50, v50, v50 quad_perm:[2,3,0,1]\n\t" \
  "v_add_f32 v51, v51, v51 quad_perm:[2,3,0,1]\n\t" \
  "v_add_f32 v52, v52, v52 quad_perm:[2,3,0,1]\n\t" \
  "v_add_f32 v53, v53, v53 quad_perm:[2,3,0,1]\n\t" \
  "v_add_f32 v54, v54, v54 quad_perm:[2,3,0,1]\n\t" \
  "v_add_f32 v55, v55, v55 quad_perm:[2,3,0,1]\n\t" \
  "v_add_f32 v50, v50, v50 row_half_mirror\n\t" \
  "v_add_f32 v51, v51, v51 row_half_mirror\n\t" \
  "v_add_f32 v52, v52, v52 row_half_mirror\n\t" \
  "v_add_f32 v53, v53, v53 row_half_mirror\n\t" \
  "v_add_f32 v54, v54, v54 row_half_mirror\n\t" \
  "v_add_f32 v55, v55, v55 row_half_mirror\n\t"

// Pre-scaled gates: r=rcp(1+exp2(s_r)), z likewise; n=fma(-2,rcp(1+exp2(u)),1),
// u = r*(a_n + bhnS) + gn (all n-terms pre-scaled by 2log2e).
// Trans hazards: every v_exp/v_rcp result consumed >=2 insts later.
// v50..v55 = reduced sums (a_r0,a_r1,a_z0,a_z1,a_n0,a_n1); h = v48,v49.
#define GATES_PS(R0, Z0, R1, Z1, N0, N1) \
  "v_add_f32 v56, " R0 ", v50\n\t" \
  "v_add_f32 v57, " R1 ", v51\n\t" \
  "v_add_f32 v58, " Z0 ", v52\n\t" \
  "v_add_f32 v59, " Z1 ", v53\n\t" \
  "v_exp_f32 v56, v56\n\t" \
  "v_exp_f32 v57, v57\n\t" \
  "v_exp_f32 v58, v58\n\t" \
  "v_exp_f32 v59, v59\n\t" \
  "v_add_f32 v56, 1.0, v56\n\t" \
  "v_add_f32 v57, 1.0, v57\n\t" \
  "v_add_f32 v58, 1.0, v58\n\t" \
  "v_add_f32 v59, 1.0, v59\n\t" \
  "v_rcp_f32 v56, v56\n\t" \
  "v_rcp_f32 v57, v57\n\t" \
  "v_rcp_f32 v58, v58\n\t" \
  "v_rcp_f32 v59, v59\n\t" \
  "v_add_f32 v50, %[bh0], v54\n\t" \
  "v_add_f32 v51, %[bh1], v55\n\t" \
  "v_fma_f32 v50, v56, v50, " N0 "\n\t" \
  "v_fma_f32 v51, v57, v51, " N1 "\n\t" \
  "v_exp_f32 v50, v50\n\t" \
  "v_exp_f32 v51, v51\n\t" \
  "s_nop 0\n\t" \
  "v_add_f32 v50, 1.0, v50\n\t" \
  "v_add_f32 v51, 1.0, v51\n\t" \
  "v_rcp_f32 v50, v50\n\t" \
  "v_rcp_f32 v51, v51\n\t" \
  "s_nop 0\n\t" \
  "v_fma_f32 v50, -2.0, v50, 1.0\n\t" \
  "v_fma_f32 v51, -2.0, v51, 1.0\n\t" \
  "v_sub_f32 v52, v48, v50\n\t" \
  "v_sub_f32 v53, v49, v51\n\t" \
  "v_fma_f32 v48, v58, v52, v50\n\t" \
  "v_fma_f32 v49, v59, v53, v51\n\t"

// =============== recurrence (l0 and l1: identical machine) ===============
// Thread: cs=tid&7 (cols [8cs,8cs+8) and [64+8cs,..)); g=tid>>3 (units 2g,2g+1).
// Rows in v100-195: u0r, u1r, u0z, u1z, u0n, u1n (16 regs each).
__device__ __forceinline__ void rec_asm(const float* __restrict__ Ws,
                                        const float* __restrict__ bhnS,
                                        const float* __restrict__ rz,
                                        const float* __restrict__ nb,
                                        float* __restrict__ hstate,
                                        float* __restrict__ h0out,
                                        float* __restrict__ outp, int c) {
  __shared__ __align__(16) float hbuf[2][HDIM];
  __shared__ __align__(16) float hdummy[1160];   // dummy sink for cs!=0 writes
  const int tid = threadIdx.x, cs = tid & 7, g = tid >> 3;
  const int u0 = 2 * g;
  float hp0 = 0.f, hp1 = 0.f;
  if (c > 0) { hp0 = hstate[u0]; hp1 = hstate[u0 + 1]; }
  const float bh0 = bhnS[u0], bh1 = bhnS[u0 + 1];
  unsigned vow  = (unsigned)(u0 * 512 + 32 * cs);   // weight row base (bytes)
  unsigned vow1 = vow + 65536u;                     // +128 rows
  unsigned vow2 = vow + 131072u;                    // +256 rows
  unsigned vorz = (unsigned)(2048 + 16 * g);        // rz stream at t=2
  unsigned vonb = (unsigned)(1024 + 8 * g);         // nb stream at t=2
  unsigned voho = (unsigned)(8 * g);                // h-out at t=0
  unsigned pa = (unsigned)(size_t)&hbuf[0][8 * cs]; // LDS read base (parity A)
  // conflict-free write: only the cs==0 lane targets hbuf; others hit dummy
  unsigned pw = (cs == 0) ? (unsigned)(size_t)&hbuf[0][u0]
                          : (unsigned)(size_t)&hdummy[2 * (tid - 1)];
  int cnt = CH / 2;

  asm volatile(
    // ---------- preamble: 24 weight loads into v100-195 ----------
    "global_load_dwordx4 v[100:103], %[vow], %[wb]\n\t"
    "global_load_dwordx4 v[104:107], %[vow], %[wb] offset:16\n\t"
    "global_load_dwordx4 v[108:111], %[vow], %[wb] offset:256\n\t"
    "global_load_dwordx4 v[112:115], %[vow], %[wb] offset:272\n\t"
    "global_load_dwordx4 v[116:119], %[vow], %[wb] offset:512\n\t"
    "global_load_dwordx4 v[120:123], %[vow], %[wb] offset:528\n\t"
    "global_load_dwordx4 v[124:127], %[vow], %[wb] offset:768\n\t"
    "global_load_dwordx4 v[128:131], %[vow], %[wb] offset:784\n\t"
    "global_load_dwordx4 v[132:135], %[vow1], %[wb]\n\t"
    "global_load_dwordx4 v[136:139], %[vow1], %[wb] offset:16\n\t"
    "global_load_dwordx4 v[140:143], %[vow1], %[wb] offset:256\n\t"
    "global_load_dwordx4 v[144:147], %[vow1], %[wb] offset:272\n\t"
    "global_load_dwordx4 v[148:151], %[vow1], %[wb] offset:512\n\t"
    "global_load_dwordx4 v[152:155], %[vow1], %[wb] offset:528\n\t"
    "global_load_dwordx4 v[156:159], %[vow1], %[wb] offset:768\n\t"
    "global_load_dwordx4 v[160:163], %[vow1], %[wb] offset:784\n\t"
    "global_load_dwordx4 v[164:167], %[vow2], %[wb]\n\t"
    "global_load_dwordx4 v[168:171], %[vow2], %[wb] offset:16\n\t"
    "global_load_dwordx4 v[172:175], %[vow2], %[wb] offset:256\n\t"
    "global_load_dwordx4 v[176:179], %[vow2], %[wb] offset:272\n\t"
    "global_load_dwordx4 v[180:183], %[vow2], %[wb] offset:512\n\t"
    "global_load_dwordx4 v[184:187], %[vow2], %[wb] offset:528\n\t"
    "global_load_dwordx4 v[188:191], %[vow2], %[wb] offset:768\n\t"
    "global_load_dwordx4 v[192:195], %[vow2], %[wb] offset:784\n\t"
    // ---------- preamble: gates(0) -> A slots, gates(1) -> B slots ----------
    "global_load_dwordx4 v[88:91], %[vorz], %[rzb] offset:-2048\n\t"
    "global_load_dwordx2 v[92:93], %[vonb], %[nbb] offset:-1024\n\t"
    "global_load_dwordx4 v[94:97], %[vorz], %[rzb] offset:-1024\n\t"
    "global_load_dwordx2 v[98:99], %[vonb], %[nbb] offset:-512\n\t"
    // ---------- h(0) into LDS buf0 ----------
    "v_mov_b32 v48, %[h0]\n\t"
    "v_mov_b32 v49, %[h1]\n\t"
    "ds_write_b64 %[pw], v[48:49]\n\t"
    "s_waitcnt vmcnt(0) lgkmcnt(0)\n\t"
    "s_barrier\n\t"
    "Lrec%=:\n\t"
    // ================= phase A (even t): h in buf0 =================
    "ds_read_b128 v[60:63], %[pa]\n\t"
    "ds_read_b128 v[64:67], %[pa] offset:16\n\t"
    "ds_read_b128 v[68:71], %[pa] offset:256\n\t"
    "ds_read_b128 v[72:75], %[pa] offset:272\n\t"
    "s_waitcnt lgkmcnt(0)\n\t"
    DOTS6
    RED6
    "s_waitcnt vmcnt(4)\n\t"
    GATES_PS("v88", "v89", "v90", "v91", "v92", "v93")
    "global_load_dwordx4 v[88:91], %[vorz], %[rzb]\n\t"
    "global_load_dwordx2 v[92:93], %[vonb], %[nbb]\n\t"
    "ds_write_b64 %[pw], v[48:49] offset:512\n\t"
    "global_store_dwordx2 %[voho], v[48:49], %[hob]\n\t"
    "s_waitcnt lgkmcnt(0)\n\t"
    "s_barrier\n\t"
    // ================= phase B (odd t): h in buf1 =================
    "ds_read_b128 v[60:63], %[pa] offset:512\n\t"
    "ds_read_b128 v[64:67], %[pa] offset:528\n\t"
    "ds_read_b128 v[68:71], %[pa] offset:768\n\t"
    "ds_read_b128 v[72:75], %[pa] offset:784\n\t"
    "s_waitcnt lgkmcnt(0)\n\t"
    DOTS6
    RED6
    "s_waitcnt vmcnt(4)\n\t"
    GATES_PS("v94", "v95", "v96", "v97", "v98", "v99")
    "global_load_dwordx4 v[94:97], %[vorz], %[rzb] offset:1024\n\t"
    "global_load_dwordx2 v[98:99], %[vonb], %[nbb] offset:512\n\t"
    "ds_write_b64 %[pw], v[48:49]\n\t"
    "global_store_dwordx2 %[voho], v[48:49], %[hob] offset:512\n\t"
    "v_add_u32 %[vorz], 2048, %[vorz]\n\t"
    "v_add_u32 %[vonb], 1024, %[vonb]\n\t"
    "v_add_u32 %[voho], 1024, %[voho]\n\t"
    "s_waitcnt lgkmcnt(0)\n\t"
    "s_barrier\n\t"
    "s_sub_u32 %[cnt], %[cnt], 1\n\t"
    "s_cmp_lg_u32 %[cnt], 0\n\t"
    "s_cbranch_scc1 Lrec%=\n\t"
    "v_mov_b32 %[h0], v48\n\t"
    "v_mov_b32 %[h1], v49\n\t"
    : [vorz]"+v"(vorz), [vonb]"+v"(vonb), [voho]"+v"(voho), [cnt]"+s"(cnt),
      [h0]"+v"(hp0), [h1]"+v"(hp1)
    : [wb]"s"(Ws), [rzb]"s"(rz), [nbb]"s"(nb), [hob]"s"(h0out),
      [vow]"v"(vow), [vow1]"v"(vow1), [vow2]"v"(vow2),
      [pa]"v"(pa), [pw]"v"(pw), [bh0]"v"(bh0), [bh1]"v"(bh1)
    : "memory", "scc",
      "v48","v49","v50","v51","v52","v53","v54","v55","v56","v57","v58","v59",
      "v60","v61","v62","v63","v64","v65","v66","v67","v68","v69","v70","v71",
      "v72","v73","v74","v75","v76","v77","v78","v79","v80","v81","v82","v83",
      "v84","v85","v86","v87","v88","v89","v90","v91","v92","v93","v94","v95",
      "v96","v97","v98","v99","v100","v101","v102","v103","v104","v105","v106",
      "v107","v108","v109","v110","v111","v112","v113","v114","v115","v116",
      "v117","v118","v119","v120","v121","v122","v123","v124","v125","v126",
      "v127","v128","v129","v130","v131","v132","v133","v134","v135","v136",
      "v137","v138","v139","v140","v141","v142","v143","v144","v145","v146",
      "v147","v148","v149","v150","v151","v152","v153","v154","v155","v156",
      "v157","v158","v159","v160","v161","v162","v163","v164","v165","v166",
      "v167","v168","v169","v170","v171","v172","v173","v174","v175","v176",
      "v177","v178","v179","v180","v181","v182","v183","v184","v185","v186",
      "v187","v188","v189","v190","v191","v192","v193","v194","v195");

  if (cs == 0) {
    hstate[u0] = hp0; hstate[u0 + 1] = hp1;
    if (outp) { outp[u0] = hp0; outp[u0 + 1] = hp1; }
  }
}

// ============== army phase A: gi0 = Wi0s @ x + bA0 (scaled) ==============
__device__ __forceinline__ void role_giA(int rb, int c, const float* __restrict__ x,
                                         const float* __restrict__ Wi0s,
                                         const float* __restrict__ bA0,
                                         float* __restrict__ rz, float* __restrict__ nb) {
  const int tid = threadIdx.x;
  const int u = tid & 127, sb = tid >> 7;
  const int row = rb * 128 + u;
  const f32x4 wa = *(const f32x4*)(Wi0s + (size_t)row * 8);
  const f32x4 wb = *(const f32x4*)(Wi0s + (size_t)row * 8 + 4);
  const float bias = bA0[row];
  const int m = u >> 1, sub = u & 1;
  for (int i = 0; i < CH / 4; ++i) {
    const int tl = sb * (CH / 4) + i;
    const float* xp = x + ((size_t)c * CH + tl) * 8;
    const f32x4 xa = *(const f32x4*)xp;
    const f32x4 xb2 = *(const f32x4*)(xp + 4);
    float acc = bias;
    acc = fmaf(wa.x, xa.x, acc); acc = fmaf(wa.y, xa.y, acc);
    acc = fmaf(wa.z, xa.z, acc); acc = fmaf(wa.w, xa.w, acc);
    acc = fmaf(wb.x, xb2.x, acc); acc = fmaf(wb.y, xb2.y, acc);
    acc = fmaf(wb.z, xb2.z, acc); acc = fmaf(wb.w, xb2.w, acc);
    if (rb < 2) rz[(size_t)tl * 256 + 4 * m + 2 * sub + rb] = acc;
    else        nb[(size_t)tl * 128 + u] = acc;
  }
}

// ============== army phase B: gi1 = Wi1s @ h0 + bA1 (scaled) ==============
__device__ __forceinline__ void role_giB(int rb, const float* __restrict__ h0src,
                                         const float* __restrict__ Wi1s,
                                         const float* __restrict__ bA1,
                                         float* __restrict__ rz, float* __restrict__ nb) {
  __shared__ __align__(16) float hsg[2][GS * HDIM];
  const int tid = threadIdx.x, cs = tid & 7, m = tid >> 3;
  const int R0 = rb * 128 + 2 * m, R1 = R0 + 1;
  f32x4 V0[4], V1[4];
  {
    const float* p0 = Wi1s + (size_t)R0 * 128 + 8 * cs;
    const float* p1 = Wi1s + (size_t)R1 * 128 + 8 * cs;
    V0[0] = *(const f32x4*)p0;        V0[1] = *(const f32x4*)(p0 + 4);
    V0[2] = *(const f32x4*)(p0 + 64); V0[3] = *(const f32x4*)(p0 + 68);
    V1[0] = *(const f32x4*)p1;        V1[1] = *(const f32x4*)(p1 + 4);
    V1[2] = *(const f32x4*)(p1 + 64); V1[3] = *(const f32x4*)(p1 + 68);
  }
  const float b0 = bA1[R0], b1 = bA1[R1];

  if (tid < 256) ((f32x4*)hsg[0])[tid] = ((const f32x4*)h0src)[tid];
  __syncthreads();
  int cur = 0;
  for (int gb = 0; gb < CH / GS; ++gb) {
    f32x4 pf;
    const bool hv = (gb + 1 < CH / GS) && (tid < 256);
    if (hv) pf = ((const f32x4*)(h0src + (size_t)(gb + 1) * (GS * HDIM)))[tid];
    #pragma unroll
    for (int s = 0; s < GS; ++s) {
      const float* hb = hsg[cur] + s * HDIM;
      const f32x4 hA = *(const f32x4*)(hb + 8 * cs);
      const f32x4 hB = *(const f32x4*)(hb + 8 * cs + 4);
      const f32x4 hC = *(const f32x4*)(hb + 64 + 8 * cs);
      const f32x4 hD = *(const f32x4*)(hb + 64 + 8 * cs + 4);
      f32x2 d0 = {0.f, 0.f}, d1 = d0;
      pkfma(d0, lo2(V0[0]), lo2(hA)); pkfma(d0, hi2(V0[0]), hi2(hA));
      pkfma(d0, lo2(V0[1]), lo2(hB)); pkfma(d0, hi2(V0[1]), hi2(hB));
      pkfma(d0, lo2(V0[2]), lo2(hC)); pkfma(d0, hi2(V0[2]), hi2(hC));
      pkfma(d0, lo2(V0[3]), lo2(hD)); pkfma(d0, hi2(V0[3]), hi2(hD));
      pkfma(d1, lo2(V1[0]), lo2(hA)); pkfma(d1, hi2(V1[0]), hi2(hA));
      pkfma(d1, lo2(V1[1]), lo2(hB)); pkfma(d1, hi2(V1[1]), hi2(hB));
      pkfma(d1, lo2(V1[2]), lo2(hC)); pkfma(d1, hi2(V1[2]), hi2(hC));
      pkfma(d1, lo2(V1[3]), lo2(hD)); pkfma(d1, hi2(V1[3]), hi2(hD));
      const float a0 = red8(d0.x + d0.y) + b0;
      const float a1 = red8(d1.x + d1.y) + b1;
      if (cs == 0) {
        const int tl = gb * GS + s;
        if (rb < 2) {
          rz[(size_t)tl * 256 + 4 * m + rb] = a0;
          rz[(size_t)tl * 256 + 4 * m + 2 + rb] = a1;
        } else {
          f32x2 nv = {a0, a1};
          *(f32x2*)(nb + (size_t)tl * 128 + 2 * m) = nv;
        }
      }
    }
    if (hv) ((f32x4*)hsg[cur ^ 1])[tid] = pf;
    __syncthreads();
    cur ^= 1;
  }
}

// =============== the pipelined kernel (5 blocks x 512 threads) ===============
__global__ __launch_bounds__(512)
void gru_pipe(const float* __restrict__ x, float* __restrict__ out,
              const float* __restrict__ W0s, const float* __restrict__ W1s,
              const float* __restrict__ Wi0s, const float* __restrict__ Wi1s,
              const float* __restrict__ bA0, const float* __restrict__ bA1,
              const float* __restrict__ bhnS0, const float* __restrict__ bhnS1,
              float* __restrict__ hstate0, float* __restrict__ hstate1,
              float* __restrict__ h0ring, float* __restrict__ gi0rz,
              float* __restrict__ gi0n, float* __restrict__ gi1rz,
              float* __restrict__ gi1n, float* __restrict__ h1dump, int k) {
  const int bid = blockIdx.x;
  if (bid == 0) {
    const int c = k - 1;
    if (c >= 0 && c < NC)
      rec_asm(W0s, bhnS0,
              gi0rz + (size_t)(c & 1) * CH * 256, gi0n + (size_t)(c & 1) * CH * 128,
              hstate0, h0ring + (size_t)(c & 1) * CH * HDIM, nullptr, c);
  } else if (bid == 1) {
    const int c = k - 3;
    if (c >= 0 && c < NC)
      rec_asm(W1s, bhnS1,
              gi1rz + (size_t)(c & 1) * CH * 256, gi1n + (size_t)(c & 1) * CH * 128,
              hstate1, h1dump, (c == NC - 1) ? out : nullptr, c);
  } else {
    const int rb = bid - 2;
    if (k < NC)
      role_giA(rb, k, x, Wi0s, bA0,
               gi0rz + (size_t)(k & 1) * CH * 256, gi0n + (size_t)(k & 1) * CH * 128);
    const int cb = k - 2;
    if (cb >= 0 && cb < NC)
      role_giB(rb, h0ring + (size_t)(cb & 1) * CH * HDIM, Wi1s, bA1,
               gi1rz + (size_t)(cb & 1) * CH * 256, gi1n + (size_t)(cb & 1) * CH * 128);
  }
}

extern "C" void kernel_launch(void* const* d_in, const int* in_sizes, int n_in,
                              void* d_out, int out_size, void* d_ws, size_t ws_size,
                              hipStream_t stream) {
  (void)in_sizes; (void)n_in; (void)out_size; (void)ws_size;
  const float* x     = (const float*)d_in[0];
  const float* w_ih0 = (const float*)d_in[1];
  const float* w_hh0 = (const float*)d_in[2];
  const float* b_ih0 = (const float*)d_in[3];
  const float* b_hh0 = (const float*)d_in[4];
  const float* w_ih1 = (const float*)d_in[5];
  const float* w_hh1 = (const float*)d_in[6];
  const float* b_ih1 = (const float*)d_in[7];
  const float* b_hh1 = (const float*)d_in[8];
  float* out = (float*)d_out;

  float* p = (float*)d_ws;
  float* W0s    = p; p += 49152;
  float* W1s    = p; p += 49152;
  float* Wi1s   = p; p += 49152;
  float* Wi0s   = p; p += 3072;
  float* bA0    = p; p += 384;
  float* bA1    = p; p += 384;
  float* bhnS0  = p; p += 128;
  float* bhnS1  = p; p += 128;
  float* hstate0 = p; p += 128;
  float* hstate1 = p; p += 128;
  float* h0ring  = p; p += (size_t)2 * CH * 128;
  float* gi0rz   = p; p += (size_t)2 * CH * 256;
  float* gi0n    = p; p += (size_t)2 * CH * 128;
  float* gi1rz   = p; p += (size_t)2 * CH * 256;
  float* gi1n    = p; p += (size_t)2 * CH * 128;
  float* h1dump  = p; p += (size_t)CH * 128;       // l1 h-store sink (unread)

  hipLaunchKernelGGL(gru_prep, dim3(192), dim3(256), 0, stream,
                     w_ih0, w_hh0, b_ih0, b_hh0, w_ih1, w_hh1, b_ih1, b_hh1,
                     W0s, W1s, Wi0s, Wi1s, bA0, bA1, bhnS0, bhnS1);
  for (int k = 0; k <= NC + 2; ++k) {
    hipLaunchKernelGGL(gru_pipe, dim3(5), dim3(512), 0, stream,
                       x, out, W0s, W1s, Wi0s, Wi1s, bA0, bA1, bhnS0, bhnS1,
                       hstate0, hstate1, h0ring, gi0rz, gi0n, gi1rz, gi1n,
                       h1dump, k);
  }
}

// Round 15
// 16308.018 us; speedup vs baseline: 1.7484x; 1.1963x over previous
//
#include <hip/hip_runtime.h>

// 2-layer GRU, I=8, H=128, T=32768 steps, out = final h1 (128 f32).
// Launch-level pipeline (proven r7-r14). Launch k, disjoint blocks:
//   blocks 2-4 (army): A: gi0 = Wi0s@x + bA0, chunk k (x-only, ahead)
//                      B: gi1 = Wi1s@h0 + bA1, chunk k-2
//   block 0 (l0): layer-0 recurrence, chunk k-1 (consumes gi0, publishes h0)
//   block 1 (l1): layer-1 recurrence, chunk k-3 (consumes gi1, writes out)
// Recurrence = one asm block, weights hard-pinned v100-195 (r13/r14-proven).
// r14 post-mortem: VALUBusy 0.776% = 2.0 CUs -> recurrence CUs are ISSUE-bound
// (pk ops are 4cy/wave64, trans ~16cy — not the 2cy assumed). Biggest waste:
// every lane computed BOTH units' gates (12 trans). r15: lane-specialized
// gates (cs<4 -> u0, cs>=4 -> u1: 6 trans/lane, cndmask-select on ballot
// mask), split lgkmcnt(2)/(0) around the dot halves, gate loads hoisted with
// exact vmcnt(6). Dot/reduce/weights asm and army/prep unchanged.

#define T_STEPS 32768
#define HDIM 128
#define CH 1024
#define NC (T_STEPS / CH)
#define GS 8

typedef __attribute__((ext_vector_type(2))) float f32x2;
typedef __attribute__((ext_vector_type(4))) float f32x4;

__device__ __forceinline__ f32x2 lo2(f32x4 v) { return __builtin_shufflevector(v, v, 0, 1); }
__device__ __forceinline__ f32x2 hi2(f32x4 v) { return __builtin_shufflevector(v, v, 2, 3); }
__device__ __forceinline__ void pkfma(f32x2& acc, f32x2 a, f32x2 b) {
  asm("v_pk_fma_f32 %0, %1, %2, %0" : "+v"(acc) : "v"(a), "v"(b));
}
__device__ __forceinline__ float red8(float v) {
  int t = __builtin_amdgcn_mov_dpp(__builtin_bit_cast(int, v), 0xB1, 0xF, 0xF, true);
  v += __builtin_bit_cast(float, t);
  t = __builtin_amdgcn_mov_dpp(__builtin_bit_cast(int, v), 0x4E, 0xF, 0xF, true);
  v += __builtin_bit_cast(float, t);
  t = __builtin_amdgcn_mov_dpp(__builtin_bit_cast(int, v), 0x141, 0xF, 0xF, true);
  v += __builtin_bit_cast(float, t);
  return v;
}

// =============== prep: scaled weight/bias copies (r14-proven, verbatim) ===============
__global__ __launch_bounds__(256)
void gru_prep(const float* __restrict__ w_ih0, const float* __restrict__ w_hh0,
              const float* __restrict__ b_ih0, const float* __restrict__ b_hh0,
              const float* __restrict__ w_ih1, const float* __restrict__ w_hh1,
              const float* __restrict__ b_ih1, const float* __restrict__ b_hh1,
              float* __restrict__ W0s, float* __restrict__ W1s,
              float* __restrict__ Wi0s, float* __restrict__ Wi1s,
              float* __restrict__ bA0, float* __restrict__ bA1,
              float* __restrict__ bhnS0, float* __restrict__ bhnS1) {
  const float SRZ = -1.4426950408889634f;   // -log2(e)
  const float SN  =  2.8853900817779268f;   // +2*log2(e)
  const int i = blockIdx.x * 256 + threadIdx.x;
  if (i < 49152) {
    const float s = ((i >> 7) < 256) ? SRZ : SN;
    W0s[i]  = w_hh0[i] * s;
    W1s[i]  = w_hh1[i] * s;
    Wi1s[i] = w_ih1[i] * s;
  }
  if (i < 3072) Wi0s[i] = w_ih0[i] * (((i >> 3) < 256) ? SRZ : SN);
  if (i < 384) {
    bA0[i] = (i < 256) ? SRZ * (b_ih0[i] + b_hh0[i]) : SN * b_ih0[i];
    bA1[i] = (i < 256) ? SRZ * (b_ih1[i] + b_hh1[i]) : SN * b_ih1[i];
  }
  if (i < 128) {
    bhnS0[i] = SN * b_hh0[256 + i];
    bhnS1[i] = SN * b_hh1[256 + i];
  }
}

// ---------------- asm building blocks ----------------
#define PKM(D, A, B) "v_pk_mul_f32 v[" D "], v[" A "], v[" B "]\n\t"
#define PKF(D, A, B) "v_pk_fma_f32 v[" D "], v[" A "], v[" B "], v[" D "]\n\t"

// first half: cols [8cs,8cs+8) via hA(v60:63),hB(v64:67); second: [64+8cs,..)
#define DOTROW_A(ACC, W0, W1, W2, W3) \
  PKM(ACC, W0, "60:61") PKF(ACC, W1, "62:63") \
  PKF(ACC, W2, "64:65") PKF(ACC, W3, "66:67")
#define DOTROW_B(ACC, W4, W5, W6, W7) \
  PKF(ACC, W4, "68:69") PKF(ACC, W5, "70:71") \
  PKF(ACC, W6, "72:73") PKF(ACC, W7, "74:75")

#define DOTS6_A \
  DOTROW_A("76:77","100:101","102:103","104:105","106:107") \
  DOTROW_A("78:79","116:117","118:119","120:121","122:123") \
  DOTROW_A("80:81","132:133","134:135","136:137","138:139") \
  DOTROW_A("82:83","148:149","150:151","152:153","154:155") \
  DOTROW_A("84:85","164:165","166:167","168:169","170:171") \
  DOTROW_A("86:87","180:181","182:183","184:185","186:187")
#define DOTS6_B \
  DOTROW_B("76:77","108:109","110:111","112:113","114:115") \
  DOTROW_B("78:79","124:125","126:127","128:129","130:131") \
  DOTROW_B("80:81","140:141","142:143","144:145","146:147") \
  DOTROW_B("82:83","156:157","158:159","160:161","162:163") \
  DOTROW_B("84:85","172:173","174:175","176:177","178:179") \
  DOTROW_B("86:87","188:189","190:191","192:193","194:195")

// stage-interleaved reduce across 6 sums (r13-proven, verbatim)
#define RED6 \
  "v_add_f32 v50, v76, v77\n\t" "v_add_f32 v51, v78, v79\n\t" \
  "v_add_f32 v52, v80, v81\n\t" "v_add_f32 v53, v82, v83\n\t" \
  "v_add_f32 v54, v84, v85\n\t" "v_add_f32 v55, v86, v87\n\t" \
  "v_add_f32 v50, v50, v50 quad_perm:[1,0,3,2]\n\t" \
  "v_add_f32 v51, v51, v51 quad_perm:[1,0,3,2]\n\t" \
  "v_add_f32 v52, v52, v52 quad_perm:[1,0,3,2]\n\t" \
  "v_add_f32 v53, v53, v53 quad_perm:[1,0,3,2]\n\t" \
  "v_add_f32 v54, v54, v54 quad_perm:[1,0,3,2]\n\t" \
  "v_add_f32 v55, v55, v55 quad_perm:[1,0,3,2]\n\t" \
  "v_add_f32 v50, v50, v50 quad_perm:[2,3,0,1]\n\t" \
  "v_add_f32 v51, v51, v51 quad_perm:[2,3,0,1]\n\t" \
  "v_add_f32 v52, v52, v52 quad_perm:[2,3,0,1]\n\t" \
  "v_add_f32 v53, v53, v53 quad_perm:[2,3,0,1]\n\t" \
  "v_add_f32 v54, v54, v54 quad_perm:[2,3,0,1]\n\t" \
  "v_add_f32 v55, v55, v55 quad_perm:[2,3,0,1]\n\t" \
  "v_add_f32 v50, v50, v50 row_half_mirror\n\t" \
  "v_add_f32 v51, v51, v51 row_half_mirror\n\t" \
  "v_add_f32 v52, v52, v52 row_half_mirror\n\t" \
  "v_add_f32 v53, v53, v53 row_half_mirror\n\t" \
  "v_add_f32 v54, v54, v54 row_half_mirror\n\t" \
  "v_add_f32 v55, v55, v55 row_half_mirror\n\t"

// Lane-specialized gates: aR=sel(v50,v51), aZ=sel(v52,v53), aN=sel(v54,v55)
// by mk=(cs&4). One unit per lane: r=rcp(1+exp2(rin+aR)); z likewise;
// n=fma(-2,rcp(1+exp2(r*(aN+bh)+nin)),1); h'=n+z*(h-n). Same per-unit
// association as r13/r14 (absmax 0.0). Trans results consumed >=2 insts later.
#define GATES_SPEC(RIN, ZIN, NIN) \
  "v_cndmask_b32 v56, v50, v51, %[mk]\n\t" \
  "v_cndmask_b32 v57, v52, v53, %[mk]\n\t" \
  "v_cndmask_b32 v58, v54, v55, %[mk]\n\t" \
  "v_add_f32 v56, " RIN ", v56\n\t" \
  "v_add_f32 v57, " ZIN ", v57\n\t" \
  "v_add_f32 v58, %[bh], v58\n\t" \
  "v_exp_f32 v56, v56\n\t" \
  "v_exp_f32 v57, v57\n\t" \
  "s_nop 0\n\t" \
  "v_add_f32 v56, 1.0, v56\n\t" \
  "v_add_f32 v57, 1.0, v57\n\t" \
  "v_rcp_f32 v56, v56\n\t" \
  "v_rcp_f32 v57, v57\n\t" \
  "s_nop 0\n\t" \
  "v_fma_f32 v59, v56, v58, " NIN "\n\t" \
  "v_exp_f32 v59, v59\n\t" \
  "s_nop 1\n\t" \
  "v_add_f32 v59, 1.0, v59\n\t" \
  "v_rcp_f32 v59, v59\n\t" \
  "s_nop 1\n\t" \
  "v_fma_f32 v59, -2.0, v59, 1.0\n\t" \
  "v_sub_f32 v49, v48, v59\n\t" \
  "v_fma_f32 v48, v57, v49, v59\n\t"

// =============== recurrence (l0 and l1: identical machine) ===============
// Thread: cs=tid&7 (cols [8cs,8cs+8) and [64+8cs,..)); g=tid>>3; units 2g,2g+1;
// this lane's unit ul = 2g + (cs>=4). Rows in v100-195 as r13.
__device__ __forceinline__ void rec_asm(const float* __restrict__ Ws,
                                        const float* __restrict__ bhnS,
                                        const float* __restrict__ rz,
                                        const float* __restrict__ nb,
                                        float* __restrict__ hstate,
                                        float* __restrict__ h0out,
                                        float* __restrict__ outp, int c) {
  __shared__ __align__(16) float hbuf[2][HDIM];
  __shared__ __align__(16) float hdummy[768];   // sink for non-writer ds_write
  const int tid = threadIdx.x, cs = tid & 7, g = tid >> 3;
  const int u0 = 2 * g;
  const int ul = u0 + ((cs & 4) ? 1 : 0);
  float hp = (c > 0) ? hstate[ul] : 0.f;
  const float bh = bhnS[ul];
  unsigned long long mk = __ballot((cs & 4) != 0);
  unsigned vow  = (unsigned)(u0 * 512 + 32 * cs);   // weight row base (bytes)
  unsigned vow1 = vow + 65536u;                     // +128 rows
  unsigned vow2 = vow + 131072u;                    // +256 rows
  unsigned vorz = (unsigned)(2048 + 8 * ul);        // rz2 stream at t=2
  unsigned vonb = (unsigned)(1024 + 4 * ul);        // nb stream at t=2
  unsigned voho = (unsigned)(4 * ul);               // h-out (4-way dup, r13-style)
  unsigned pa = (unsigned)(size_t)&hbuf[0][8 * cs]; // LDS read base (parity A)
  unsigned pw = ((cs & 3) == 0) ? (unsigned)(size_t)&hbuf[0][ul]
                                : (unsigned)(size_t)&hdummy[tid];
  int cnt = CH / 2;

  asm volatile(
    // ---------- preamble: 24 weight loads into v100-195 (r13-verbatim) ----------
    "global_load_dwordx4 v[100:103], %[vow], %[wb]\n\t"
    "global_load_dwordx4 v[104:107], %[vow], %[wb] offset:16\n\t"
    "global_load_dwordx4 v[108:111], %[vow], %[wb] offset:256\n\t"
    "global_load_dwordx4 v[112:115], %[vow], %[wb] offset:272\n\t"
    "global_load_dwordx4 v[116:119], %[vow], %[wb] offset:512\n\t"
    "global_load_dwordx4 v[120:123], %[vow], %[wb] offset:528\n\t"
    "global_load_dwordx4 v[124:127], %[vow], %[wb] offset:768\n\t"
    "global_load_dwordx4 v[128:131], %[vow], %[wb] offset:784\n\t"
    "global_load_dwordx4 v[132:135], %[vow1], %[wb]\n\t"
    "global_load_dwordx4 v[136:139], %[vow1], %[wb] offset:16\n\t"
    "global_load_dwordx4 v[140:143], %[vow1], %[wb] offset:256\n\t"
    "global_load_dwordx4 v[144:147], %[vow1], %[wb] offset:272\n\t"
    "global_load_dwordx4 v[148:151], %[vow1], %[wb] offset:512\n\t"
    "global_load_dwordx4 v[152:155], %[vow1], %[wb] offset:528\n\t"
    "global_load_dwordx4 v[156:159], %[vow1], %[wb] offset:768\n\t"
    "global_load_dwordx4 v[160:163], %[vow1], %[wb] offset:784\n\t"
    "global_load_dwordx4 v[164:167], %[vow2], %[wb]\n\t"
    "global_load_dwordx4 v[168:171], %[vow2], %[wb] offset:16\n\t"
    "global_load_dwordx4 v[172:175], %[vow2], %[wb] offset:256\n\t"
    "global_load_dwordx4 v[176:179], %[vow2], %[wb] offset:272\n\t"
    "global_load_dwordx4 v[180:183], %[vow2], %[wb] offset:512\n\t"
    "global_load_dwordx4 v[184:187], %[vow2], %[wb] offset:528\n\t"
    "global_load_dwordx4 v[188:191], %[vow2], %[wb] offset:768\n\t"
    "global_load_dwordx4 v[192:195], %[vow2], %[wb] offset:784\n\t"
    // ---------- preamble: per-lane gates(0) -> A slots, gates(1) -> B ----------
    "global_load_dwordx2 v[88:89], %[vorz], %[rzb] offset:-2048\n\t"
    "global_load_dword v92, %[vonb], %[nbb] offset:-1024\n\t"
    "global_load_dwordx2 v[90:91], %[vorz], %[rzb] offset:-1024\n\t"
    "global_load_dword v93, %[vonb], %[nbb] offset:-512\n\t"
    // ---------- h(0) into LDS buf0 ----------
    "v_mov_b32 v48, %[h0]\n\t"
    "ds_write_b32 %[pw], v48\n\t"
    "s_waitcnt vmcnt(0) lgkmcnt(0)\n\t"
    "s_barrier\n\t"
    "Lrec%=:\n\t"
    // ================= phase A (even t): h in buf0 =================
    "ds_read_b128 v[60:63], %[pa]\n\t"
    "ds_read_b128 v[64:67], %[pa] offset:16\n\t"
    "ds_read_b128 v[68:71], %[pa] offset:256\n\t"
    "ds_read_b128 v[72:75], %[pa] offset:272\n\t"
    "s_waitcnt lgkmcnt(2)\n\t"
    DOTS6_A
    "s_waitcnt lgkmcnt(0)\n\t"
    DOTS6_B
    RED6
    "global_load_dwordx2 v[88:89], %[vorz], %[rzb]\n\t"
    "global_load_dword v92, %[vonb], %[nbb]\n\t"
    "s_waitcnt vmcnt(6)\n\t"
    GATES_SPEC("v88", "v89", "v92")
    "ds_write_b32 %[pw], v48 offset:512\n\t"
    "global_store_dword %[voho], v48, %[hob]\n\t"
    "s_waitcnt lgkmcnt(0)\n\t"
    "s_barrier\n\t"
    // ================= phase B (odd t): h in buf1 =================
    "ds_read_b128 v[60:63], %[pa] offset:512\n\t"
    "ds_read_b128 v[64:67], %[pa] offset:528\n\t"
    "ds_read_b128 v[68:71], %[pa] offset:768\n\t"
    "ds_read_b128 v[72:75], %[pa] offset:784\n\t"
    "s_waitcnt lgkmcnt(2)\n\t"
    DOTS6_A
    "s_waitcnt lgkmcnt(0)\n\t"
    DOTS6_B
    RED6
    "global_load_dwordx2 v[90:91], %[vorz], %[rzb] offset:1024\n\t"
    "global_load_dword v93, %[vonb], %[nbb] offset:512\n\t"
    "s_waitcnt vmcnt(6)\n\t"
    GATES_SPEC("v90", "v91", "v93")
    "ds_write_b32 %[pw], v48\n\t"
    "global_store_dword %[voho], v48, %[hob] offset:512\n\t"
    "v_add_u32 %[vorz], 2048, %[vorz]\n\t"
    "v_add_u32 %[vonb], 1024, %[vonb]\n\t"
    "v_add_u32 %[voho], 1024, %[voho]\n\t"
    "s_waitcnt lgkmcnt(0)\n\t"
    "s_barrier\n\t"
    "s_sub_u32 %[cnt], %[cnt], 1\n\t"
    "s_cmp_lg_u32 %[cnt], 0\n\t"
    "s_cbranch_scc1 Lrec%=\n\t"
    "v_mov_b32 %[h0], v48\n\t"
    : [vorz]"+v"(vorz), [vonb]"+v"(vonb), [voho]"+v"(voho), [cnt]"+s"(cnt),
      [h0]"+v"(hp)
    : [wb]"s"(Ws), [rzb]"s"(rz), [nbb]"s"(nb), [hob]"s"(h0out),
      [vow]"v"(vow), [vow1]"v"(vow1), [vow2]"v"(vow2),
      [pa]"v"(pa), [pw]"v"(pw), [bh]"v"(bh), [mk]"s"(mk)
    : "memory", "scc",
      "v48","v49","v50","v51","v52","v53","v54","v55","v56","v57","v58","v59",
      "v60","v61","v62","v63","v64","v65","v66","v67","v68","v69","v70","v71",
      "v72","v73","v74","v75","v76","v77","v78","v79","v80","v81","v82","v83",
      "v84","v85","v86","v87","v88","v89","v90","v91","v92","v93","v94","v95",
      "v96","v97","v98","v99","v100","v101","v102","v103","v104","v105","v106",
      "v107","v108","v109","v110","v111","v112","v113","v114","v115","v116",
      "v117","v118","v119","v120","v121","v122","v123","v124","v125","v126",
      "v127","v128","v129","v130","v131","v132","v133","v134","v135","v136",
      "v137","v138","v139","v140","v141","v142","v143","v144","v145","v146",
      "v147","v148","v149","v150","v151","v152","v153","v154","v155","v156",
      "v157","v158","v159","v160","v161","v162","v163","v164","v165","v166",
      "v167","v168","v169","v170","v171","v172","v173","v174","v175","v176",
      "v177","v178","v179","v180","v181","v182","v183","v184","v185","v186",
      "v187","v188","v189","v190","v191","v192","v193","v194","v195");

  if ((cs & 3) == 0) {
    hstate[ul] = hp;
    if (outp) outp[ul] = hp;
  }
}

// ============== army phase A: gi0 = Wi0s @ x + bA0 (r14-proven) ==============
__device__ __forceinline__ void role_giA(int rb, int c, const float* __restrict__ x,
                                         const float* __restrict__ Wi0s,
                                         const float* __restrict__ bA0,
                                         float* __restrict__ rz, float* __restrict__ nb) {
  const int tid = threadIdx.x;
  const int u = tid & 127, sb = tid >> 7;
  const int row = rb * 128 + u;
  const f32x4 wa = *(const f32x4*)(Wi0s + (size_t)row * 8);
  const f32x4 wb = *(const f32x4*)(Wi0s + (size_t)row * 8 + 4);
  const float bias = bA0[row];
  const int m = u >> 1, sub = u & 1;
  for (int i = 0; i < CH / 4; ++i) {
    const int tl = sb * (CH / 4) + i;
    const float* xp = x + ((size_t)c * CH + tl) * 8;
    const f32x4 xa = *(const f32x4*)xp;
    const f32x4 xb2 = *(const f32x4*)(xp + 4);
    float acc = bias;
    acc = fmaf(wa.x, xa.x, acc); acc = fmaf(wa.y, xa.y, acc);
    acc = fmaf(wa.z, xa.z, acc); acc = fmaf(wa.w, xa.w, acc);
    acc = fmaf(wb.x, xb2.x, acc); acc = fmaf(wb.y, xb2.y, acc);
    acc = fmaf(wb.z, xb2.z, acc); acc = fmaf(wb.w, xb2.w, acc);
    if (rb < 2) rz[(size_t)tl * 256 + 4 * m + 2 * sub + rb] = acc;
    else        nb[(size_t)tl * 128 + u] = acc;
  }
}

// ============== army phase B: gi1 = Wi1s @ h0 + bA1 (r14-proven) ==============
__device__ __forceinline__ void role_giB(int rb, const float* __restrict__ h0src,
                                         const float* __restrict__ Wi1s,
                                         const float* __restrict__ bA1,
                                         float* __restrict__ rz, float* __restrict__ nb) {
  __shared__ __align__(16) float hsg[2][GS * HDIM];
  const int tid = threadIdx.x, cs = tid & 7, m = tid >> 3;
  const int R0 = rb * 128 + 2 * m, R1 = R0 + 1;
  f32x4 V0[4], V1[4];
  {
    const float* p0 = Wi1s + (size_t)R0 * 128 + 8 * cs;
    const float* p1 = Wi1s + (size_t)R1 * 128 + 8 * cs;
    V0[0] = *(const f32x4*)p0;        V0[1] = *(const f32x4*)(p0 + 4);
    V0[2] = *(const f32x4*)(p0 + 64); V0[3] = *(const f32x4*)(p0 + 68);
    V1[0] = *(const f32x4*)p1;        V1[1] = *(const f32x4*)(p1 + 4);
    V1[2] = *(const f32x4*)(p1 + 64); V1[3] = *(const f32x4*)(p1 + 68);
  }
  const float b0 = bA1[R0], b1 = bA1[R1];

  if (tid < 256) ((f32x4*)hsg[0])[tid] = ((const f32x4*)h0src)[tid];
  __syncthreads();
  int cur = 0;
  for (int gb = 0; gb < CH / GS; ++gb) {
    f32x4 pf;
    const bool hv = (gb + 1 < CH / GS) && (tid < 256);
    if (hv) pf = ((const f32x4*)(h0src + (size_t)(gb + 1) * (GS * HDIM)))[tid];
    #pragma unroll
    for (int s = 0; s < GS; ++s) {
      const float* hb = hsg[cur] + s * HDIM;
      const f32x4 hA = *(const f32x4*)(hb + 8 * cs);
      const f32x4 hB = *(const f32x4*)(hb + 8 * cs + 4);
      const f32x4 hC = *(const f32x4*)(hb + 64 + 8 * cs);
      const f32x4 hD = *(const f32x4*)(hb + 64 + 8 * cs + 4);
      f32x2 d0 = {0.f, 0.f}, d1 = d0;
      pkfma(d0, lo2(V0[0]), lo2(hA)); pkfma(d0, hi2(V0[0]), hi2(hA));
      pkfma(d0, lo2(V0[1]), lo2(hB)); pkfma(d0, hi2(V0[1]), hi2(hB));
      pkfma(d0, lo2(V0[2]), lo2(hC)); pkfma(d0, hi2(V0[2]), hi2(hC));
      pkfma(d0, lo2(V0[3]), lo2(hD)); pkfma(d0, hi2(V0[3]), hi2(hD));
      pkfma(d1, lo2(V1[0]), lo2(hA)); pkfma(d1, hi2(V1[0]), hi2(hA));
      pkfma(d1, lo2(V1[1]), lo2(hB)); pkfma(d1, hi2(V1[1]), hi2(hB));
      pkfma(d1, lo2(V1[2]), lo2(hC)); pkfma(d1, hi2(V1[2]), hi2(hC));
      pkfma(d1, lo2(V1[3]), lo2(hD)); pkfma(d1, hi2(V1[3]), hi2(hD));
      const float a0 = red8(d0.x + d0.y) + b0;
      const float a1 = red8(d1.x + d1.y) + b1;
      if (cs == 0) {
        const int tl = gb * GS + s;
        if (rb < 2) {
          rz[(size_t)tl * 256 + 4 * m + rb] = a0;
          rz[(size_t)tl * 256 + 4 * m + 2 + rb] = a1;
        } else {
          f32x2 nv = {a0, a1};
          *(f32x2*)(nb + (size_t)tl * 128 + 2 * m) = nv;
        }
      }
    }
    if (hv) ((f32x4*)hsg[cur ^ 1])[tid] = pf;
    __syncthreads();
    cur ^= 1;
  }
}

// =============== the pipelined kernel (5 blocks x 512 threads) ===============
__global__ __launch_bounds__(512)
void gru_pipe(const float* __restrict__ x, float* __restrict__ out,
              const float* __restrict__ W0s, const float* __restrict__ W1s,
              const float* __restrict__ Wi0s, const float* __restrict__ Wi1s,
              const float* __restrict__ bA0, const float* __restrict__ bA1,
              const float* __restrict__ bhnS0, const float* __restrict__ bhnS1,
              float* __restrict__ hstate0, float* __restrict__ hstate1,
              float* __restrict__ h0ring, float* __restrict__ gi0rz,
              float* __restrict__ gi0n, float* __restrict__ gi1rz,
              float* __restrict__ gi1n, float* __restrict__ h1dump, int k) {
  const int bid = blockIdx.x;
  if (bid == 0) {
    const int c = k - 1;
    if (c >= 0 && c < NC)
      rec_asm(W0s, bhnS0,
              gi0rz + (size_t)(c & 1) * CH * 256, gi0n + (size_t)(c & 1) * CH * 128,
              hstate0, h0ring + (size_t)(c & 1) * CH * HDIM, nullptr, c);
  } else if (bid == 1) {
    const int c = k - 3;
    if (c >= 0 && c < NC)
      rec_asm(W1s, bhnS1,
              gi1rz + (size_t)(c & 1) * CH * 256, gi1n + (size_t)(c & 1) * CH * 128,
              hstate1, h1dump, (c == NC - 1) ? out : nullptr, c);
  } else {
    const int rb = bid - 2;
    if (k < NC)
      role_giA(rb, k, x, Wi0s, bA0,
               gi0rz + (size_t)(k & 1) * CH * 256, gi0n + (size_t)(k & 1) * CH * 128);
    const int cb = k - 2;
    if (cb >= 0 && cb < NC)
      role_giB(rb, h0ring + (size_t)(cb & 1) * CH * HDIM, Wi1s, bA1,
               gi1rz + (size_t)(cb & 1) * CH * 256, gi1n + (size_t)(cb & 1) * CH * 128);
  }
}

extern "C" void kernel_launch(void* const* d_in, const int* in_sizes, int n_in,
                              void* d_out, int out_size, void* d_ws, size_t ws_size,
                              hipStream_t stream) {
  (void)in_sizes; (void)n_in; (void)out_size; (void)ws_size;
  const float* x     = (const float*)d_in[0];
  const float* w_ih0 = (const float*)d_in[1];
  const float* w_hh0 = (const float*)d_in[2];
  const float* b_ih0 = (const float*)d_in[3];
  const float* b_hh0 = (const float*)d_in[4];
  const float* w_ih1 = (const float*)d_in[5];
  const float* w_hh1 = (const float*)d_in[6];
  const float* b_ih1 = (const float*)d_in[7];
  const float* b_hh1 = (const float*)d_in[8];
  float* out = (float*)d_out;

  float* p = (float*)d_ws;
  float* W0s    = p; p += 49152;
  float* W1s    = p; p += 49152;
  float* Wi1s   = p; p += 49152;
  float* Wi0s   = p; p += 3072;
  float* bA0    = p; p += 384;
  float* bA1    = p; p += 384;
  float* bhnS0  = p; p += 128;
  float* bhnS1  = p; p += 128;
  float* hstate0 = p; p += 128;
  float* hstate1 = p; p += 128;
  float* h0ring  = p; p += (size_t)2 * CH * 128;
  float* gi0rz   = p; p += (size_t)2 * CH * 256;
  float* gi0n    = p; p += (size_t)2 * CH * 128;
  float* gi1rz   = p; p += (size_t)2 * CH * 256;
  float* gi1n    = p; p += (size_t)2 * CH * 128;
  float* h1dump  = p; p += (size_t)CH * 128;       // l1 h-store sink (unread)

  hipLaunchKernelGGL(gru_prep, dim3(192), dim3(256), 0, stream,
                     w_ih0, w_hh0, b_ih0, b_hh0, w_ih1, w_hh1, b_ih1, b_hh1,
                     W0s, W1s, Wi0s, Wi1s, bA0, bA1, bhnS0, bhnS1);
  for (int k = 0; k <= NC + 2; ++k) {
    hipLaunchKernelGGL(gru_pipe, dim3(5), dim3(512), 0, stream,
                       x, out, W0s, W1s, Wi0s, Wi1s, bA0, bA1, bhnS0, bhnS1,
                       hstate0, hstate1, h0ring, gi0rz, gi0n, gi1rz, gi1n,
                       h1dump, k);
  }
}

// Round 17
// 14451.878 us; speedup vs baseline: 1.9730x; 1.1284x over previous
//
#include <hip/hip_runtime.h>

// 2-layer GRU, I=8, H=128, T=32768 steps, out = final h1 (128 f32).
// Launch-level pipeline (proven r7-r15). Launch k, disjoint blocks:
//   blocks 2-4 (army): A: gi0 = Wi0s@x + bA0, chunk k (x-only, ahead)
//                      B: gi1 = Wi1s@h0 + bA1, chunk k-2
//   block 0 (l0): layer-0 recurrence, chunk k-1 (consumes gi0, publishes h0)
//   block 1 (l1): layer-1 recurrence, chunk k-3 (consumes gi1, writes out)
// r16 structure (1 recurrence wave/SIMD, 192 weight VGPRs hard-pinned in one
// asm block, 4-lane quad reduce, lane-specialized gates, swizzled hbuf).
// r16 compile fix: gate B-slot pair v[15:16] (odd-aligned, illegal tuple) ->
// v[16:17], n-scalar -> v18. Everything else identical.

#define T_STEPS 32768
#define HDIM 128
#define CH 1024
#define NC (T_STEPS / CH)
#define GS 8

typedef __attribute__((ext_vector_type(2))) float f32x2;
typedef __attribute__((ext_vector_type(4))) float f32x4;

__device__ __forceinline__ f32x2 lo2(f32x4 v) { return __builtin_shufflevector(v, v, 0, 1); }
__device__ __forceinline__ f32x2 hi2(f32x4 v) { return __builtin_shufflevector(v, v, 2, 3); }
__device__ __forceinline__ void pkfma(f32x2& acc, f32x2 a, f32x2 b) {
  asm("v_pk_fma_f32 %0, %1, %2, %0" : "+v"(acc) : "v"(a), "v"(b));
}
__device__ __forceinline__ float red8(float v) {
  int t = __builtin_amdgcn_mov_dpp(__builtin_bit_cast(int, v), 0xB1, 0xF, 0xF, true);
  v += __builtin_bit_cast(float, t);
  t = __builtin_amdgcn_mov_dpp(__builtin_bit_cast(int, v), 0x4E, 0xF, 0xF, true);
  v += __builtin_bit_cast(float, t);
  t = __builtin_amdgcn_mov_dpp(__builtin_bit_cast(int, v), 0x141, 0xF, 0xF, true);
  v += __builtin_bit_cast(float, t);
  return v;
}

// =============== prep: scaled weight/bias copies (r14/r15-proven) ===============
__global__ __launch_bounds__(256)
void gru_prep(const float* __restrict__ w_ih0, const float* __restrict__ w_hh0,
              const float* __restrict__ b_ih0, const float* __restrict__ b_hh0,
              const float* __restrict__ w_ih1, const float* __restrict__ w_hh1,
              const float* __restrict__ b_ih1, const float* __restrict__ b_hh1,
              float* __restrict__ W0s, float* __restrict__ W1s,
              float* __restrict__ Wi0s, float* __restrict__ Wi1s,
              float* __restrict__ bA0, float* __restrict__ bA1,
              float* __restrict__ bhnS0, float* __restrict__ bhnS1) {
  const float SRZ = -1.4426950408889634f;   // -log2(e)
  const float SN  =  2.8853900817779268f;   // +2*log2(e)
  const int i = blockIdx.x * 256 + threadIdx.x;
  if (i < 49152) {
    const float s = ((i >> 7) < 256) ? SRZ : SN;
    W0s[i]  = w_hh0[i] * s;
    W1s[i]  = w_hh1[i] * s;
    Wi1s[i] = w_ih1[i] * s;
  }
  if (i < 3072) Wi0s[i] = w_ih0[i] * (((i >> 3) < 256) ? SRZ : SN);
  if (i < 384) {
    bA0[i] = (i < 256) ? SRZ * (b_ih0[i] + b_hh0[i]) : SN * b_ih0[i];
    bA1[i] = (i < 256) ? SRZ * (b_ih1[i] + b_hh1[i]) : SN * b_ih1[i];
  }
  if (i < 128) {
    bhnS0[i] = SN * b_hh0[256 + i];
    bhnS1[i] = SN * b_hh1[256 + i];
  }
}

// ---------------- asm building blocks ----------------
#define PKM(D, A, B) "v_pk_mul_f32 v[" D "], v[" A "], v[" B "]\n\t"
#define PKF(D, A, B) "v_pk_fma_f32 v[" D "], v[" A "], v[" B "], v[" D "]\n\t"

// Row-half over h cols 0-15 of the slice (v32-47) / 16-31 (v48-63).
#define ROW8A(OP0, ACC, W0, W1, W2, W3, W4, W5, W6, W7) \
  OP0(ACC, W0, "32:33") PKF(ACC, W1, "34:35") PKF(ACC, W2, "36:37") \
  PKF(ACC, W3, "38:39") PKF(ACC, W4, "40:41") PKF(ACC, W5, "42:43") \
  PKF(ACC, W6, "44:45") PKF(ACC, W7, "46:47")
#define ROW8B(ACC, W0, W1, W2, W3, W4, W5, W6, W7) \
  PKF(ACC, W0, "48:49") PKF(ACC, W1, "50:51") PKF(ACC, W2, "52:53") \
  PKF(ACC, W3, "54:55") PKF(ACC, W4, "56:57") PKF(ACC, W5, "58:59") \
  PKF(ACC, W6, "60:61") PKF(ACC, W7, "62:63")

#define DOTS_A \
  ROW8A(PKM, "20:21", "64:65","66:67","68:69","70:71","72:73","74:75","76:77","78:79") \
  ROW8A(PKM, "22:23", "96:97","98:99","100:101","102:103","104:105","106:107","108:109","110:111") \
  ROW8A(PKM, "24:25", "128:129","130:131","132:133","134:135","136:137","138:139","140:141","142:143") \
  ROW8A(PKM, "26:27", "160:161","162:163","164:165","166:167","168:169","170:171","172:173","174:175") \
  ROW8A(PKM, "28:29", "192:193","194:195","196:197","198:199","200:201","202:203","204:205","206:207") \
  ROW8A(PKM, "30:31", "224:225","226:227","228:229","230:231","232:233","234:235","236:237","238:239")
#define DOTS_B \
  ROW8B("20:21", "80:81","82:83","84:85","86:87","88:89","90:91","92:93","94:95") \
  ROW8B("22:23", "112:113","114:115","116:117","118:119","120:121","122:123","124:125","126:127") \
  ROW8B("24:25", "144:145","146:147","148:149","150:151","152:153","154:155","156:157","158:159") \
  ROW8B("26:27", "176:177","178:179","180:181","182:183","184:185","186:187","188:189","190:191") \
  ROW8B("28:29", "208:209","210:211","212:213","214:215","216:217","218:219","220:221","222:223") \
  ROW8B("30:31", "240:241","242:243","244:245","246:247","248:249","250:251","252:253","254:255")

// 4-lane quad reduce (xor1, xor2) + unit selection by mk = ballot(cs&2).
// Pre-adds into v32-37 (h regs free after dots); DPP def->use distance >= 5.
#define RED2 \
  "v_add_f32 v32, v20, v21\n\t" "v_add_f32 v33, v22, v23\n\t" \
  "v_add_f32 v34, v24, v25\n\t" "v_add_f32 v35, v26, v27\n\t" \
  "v_add_f32 v36, v28, v29\n\t" "v_add_f32 v37, v30, v31\n\t" \
  "v_add_f32 v32, v32, v32 quad_perm:[1,0,3,2]\n\t" \
  "v_add_f32 v33, v33, v33 quad_perm:[1,0,3,2]\n\t" \
  "v_add_f32 v34, v34, v34 quad_perm:[1,0,3,2]\n\t" \
  "v_add_f32 v35, v35, v35 quad_perm:[1,0,3,2]\n\t" \
  "v_add_f32 v36, v36, v36 quad_perm:[1,0,3,2]\n\t" \
  "v_add_f32 v37, v37, v37 quad_perm:[1,0,3,2]\n\t" \
  "v_add_f32 v32, v32, v32 quad_perm:[2,3,0,1]\n\t" \
  "v_add_f32 v33, v33, v33 quad_perm:[2,3,0,1]\n\t" \
  "v_add_f32 v34, v34, v34 quad_perm:[2,3,0,1]\n\t" \
  "v_add_f32 v35, v35, v35 quad_perm:[2,3,0,1]\n\t" \
  "v_add_f32 v36, v36, v36 quad_perm:[2,3,0,1]\n\t" \
  "v_add_f32 v37, v37, v37 quad_perm:[2,3,0,1]\n\t" \
  "v_cndmask_b32 v38, v32, v33, %[mk]\n\t" \
  "v_cndmask_b32 v39, v34, v35, %[mk]\n\t" \
  "v_cndmask_b32 v40, v36, v37, %[mk]\n\t"

// One gate chain per lane (r15-proven hazard spacing): r=rcp(1+exp2(rin+aR)),
// z likewise, n=1-2*rcp(1+exp2(r*(aN+bh)+nin)), h'=n+z*(h-n).
#define GATES1(RIN, ZIN, NIN) \
  "v_add_f32 v41, " RIN ", v38\n\t" \
  "v_add_f32 v42, " ZIN ", v39\n\t" \
  "v_add_f32 v43, %[bh], v40\n\t" \
  "v_exp_f32 v41, v41\n\t" \
  "v_exp_f32 v42, v42\n\t" \
  "s_nop 0\n\t" \
  "v_add_f32 v41, 1.0, v41\n\t" \
  "v_add_f32 v42, 1.0, v42\n\t" \
  "v_rcp_f32 v41, v41\n\t" \
  "v_rcp_f32 v42, v42\n\t" \
  "s_nop 0\n\t" \
  "v_fma_f32 v44, v41, v43, " NIN "\n\t" \
  "v_exp_f32 v44, v44\n\t" \
  "s_nop 1\n\t" \
  "v_add_f32 v44, 1.0, v44\n\t" \
  "v_rcp_f32 v44, v44\n\t" \
  "s_nop 1\n\t" \
  "v_fma_f32 v44, -2.0, v44, 1.0\n\t" \
  "v_sub_f32 v43, %[h0], v44\n\t" \
  "v_fma_f32 %[h0], v42, v43, v44\n\t"

// =============== recurrence: 256 threads, 1 wave/SIMD ===============
// Thread: cs=tid&3 (cols [32cs,32cs+32)); g=tid>>2 (units 2g,2g+1); lane's
// unit ul = 2g + ((cs&2)>>1). Weights v64-255: (u0,r)(u1,r)(u0,z)(u1,z)
// (u0,n)(u1,n) x 32 regs. hbuf swizzled: col w at word w + 4*(w>>5),
// stride 144 -> the 4 col-slices hit disjoint bank quads.
__device__ __forceinline__ void rec_asm(const float* __restrict__ Ws,
                                        const float* __restrict__ bhnS,
                                        const float* __restrict__ rz,
                                        const float* __restrict__ nb,
                                        float* __restrict__ hstate,
                                        float* __restrict__ h0out,
                                        float* __restrict__ outp, int c) {
  __shared__ __align__(16) float hbuf[2][144];
  __shared__ __align__(16) float hdummy[256];
  const int tid = threadIdx.x, cs = tid & 3, g = tid >> 2;
  const int u0 = 2 * g;
  const int ul = u0 + ((cs & 2) >> 1);
  float hp = (c > 0) ? hstate[ul] : 0.f;
  const float bh = bhnS[ul];
  unsigned long long mk = __ballot((cs & 2) != 0);
  const unsigned wrd = (unsigned)(ul + 4 * (ul >> 5));        // swizzled word
  unsigned vow  = (unsigned)(u0 * 512 + 128 * cs);            // weight base (bytes)
  unsigned vorz = (unsigned)(2048 + 8 * ul);                  // rz stream at t=2
  unsigned vonb = (unsigned)(1024 + 4 * ul);                  // nb stream at t=2
  unsigned voho = (unsigned)(4 * ul);                         // h-out
  unsigned pa = (unsigned)(size_t)&hbuf[0][36 * cs];          // read base (144cs B)
  unsigned pw = ((cs & 1) == 0) ? (unsigned)(size_t)&hbuf[0][wrd]
                                : (unsigned)(size_t)&hdummy[tid];
  int cnt = CH / 2;

  asm volatile(
    // ---- preamble: z/n weight bases, 48 weight loads into v64-255 ----
    "v_add_u32 v45, 0x10000, %[vow]\n\t"
    "v_add_u32 v46, 0x20000, %[vow]\n\t"
    "global_load_dwordx4 v[64:67], %[vow], %[wb]\n\t"
    "global_load_dwordx4 v[68:71], %[vow], %[wb] offset:16\n\t"
    "global_load_dwordx4 v[72:75], %[vow], %[wb] offset:32\n\t"
    "global_load_dwordx4 v[76:79], %[vow], %[wb] offset:48\n\t"
    "global_load_dwordx4 v[80:83], %[vow], %[wb] offset:64\n\t"
    "global_load_dwordx4 v[84:87], %[vow], %[wb] offset:80\n\t"
    "global_load_dwordx4 v[88:91], %[vow], %[wb] offset:96\n\t"
    "global_load_dwordx4 v[92:95], %[vow], %[wb] offset:112\n\t"
    "global_load_dwordx4 v[96:99], %[vow], %[wb] offset:512\n\t"
    "global_load_dwordx4 v[100:103], %[vow], %[wb] offset:528\n\t"
    "global_load_dwordx4 v[104:107], %[vow], %[wb] offset:544\n\t"
    "global_load_dwordx4 v[108:111], %[vow], %[wb] offset:560\n\t"
    "global_load_dwordx4 v[112:115], %[vow], %[wb] offset:576\n\t"
    "global_load_dwordx4 v[116:119], %[vow], %[wb] offset:592\n\t"
    "global_load_dwordx4 v[120:123], %[vow], %[wb] offset:608\n\t"
    "global_load_dwordx4 v[124:127], %[vow], %[wb] offset:624\n\t"
    "global_load_dwordx4 v[128:131], v45, %[wb]\n\t"
    "global_load_dwordx4 v[132:135], v45, %[wb] offset:16\n\t"
    "global_load_dwordx4 v[136:139], v45, %[wb] offset:32\n\t"
    "global_load_dwordx4 v[140:143], v45, %[wb] offset:48\n\t"
    "global_load_dwordx4 v[144:147], v45, %[wb] offset:64\n\t"
    "global_load_dwordx4 v[148:151], v45, %[wb] offset:80\n\t"
    "global_load_dwordx4 v[152:155], v45, %[wb] offset:96\n\t"
    "global_load_dwordx4 v[156:159], v45, %[wb] offset:112\n\t"
    "global_load_dwordx4 v[160:163], v45, %[wb] offset:512\n\t"
    "global_load_dwordx4 v[164:167], v45, %[wb] offset:528\n\t"
    "global_load_dwordx4 v[168:171], v45, %[wb] offset:544\n\t"
    "global_load_dwordx4 v[172:175], v45, %[wb] offset:560\n\t"
    "global_load_dwordx4 v[176:179], v45, %[wb] offset:576\n\t"
    "global_load_dwordx4 v[180:183], v45, %[wb] offset:592\n\t"
    "global_load_dwordx4 v[184:187], v45, %[wb] offset:608\n\t"
    "global_load_dwordx4 v[188:191], v45, %[wb] offset:624\n\t"
    "global_load_dwordx4 v[192:195], v46, %[wb]\n\t"
    "global_load_dwordx4 v[196:199], v46, %[wb] offset:16\n\t"
    "global_load_dwordx4 v[200:203], v46, %[wb] offset:32\n\t"
    "global_load_dwordx4 v[204:207], v46, %[wb] offset:48\n\t"
    "global_load_dwordx4 v[208:211], v46, %[wb] offset:64\n\t"
    "global_load_dwordx4 v[212:215], v46, %[wb] offset:80\n\t"
    "global_load_dwordx4 v[216:219], v46, %[wb] offset:96\n\t"
    "global_load_dwordx4 v[220:223], v46, %[wb] offset:112\n\t"
    "global_load_dwordx4 v[224:227], v46, %[wb] offset:512\n\t"
    "global_load_dwordx4 v[228:231], v46, %[wb] offset:528\n\t"
    "global_load_dwordx4 v[232:235], v46, %[wb] offset:544\n\t"
    "global_load_dwordx4 v[236:239], v46, %[wb] offset:560\n\t"
    "global_load_dwordx4 v[240:243], v46, %[wb] offset:576\n\t"
    "global_load_dwordx4 v[244:247], v46, %[wb] offset:592\n\t"
    "global_load_dwordx4 v[248:251], v46, %[wb] offset:608\n\t"
    "global_load_dwordx4 v[252:255], v46, %[wb] offset:624\n\t"
    // ---- preamble: gates t=0 -> A slots (v12-14), t=1 -> B (v16-18) ----
    "global_load_dwordx2 v[12:13], %[vorz], %[rzb] offset:-2048\n\t"
    "global_load_dword v14, %[vonb], %[nbb] offset:-1024\n\t"
    "global_load_dwordx2 v[16:17], %[vorz], %[rzb] offset:-1024\n\t"
    "global_load_dword v18, %[vonb], %[nbb] offset:-512\n\t"
    // ---- h(0) into swizzled buf0 ----
    "ds_write_b32 %[pw], %[h0]\n\t"
    "s_waitcnt vmcnt(0) lgkmcnt(0)\n\t"
    "s_barrier\n\t"
    "Lrec%=:\n\t"
    // ================= phase A (even t): h in buf0 =================
    "ds_read_b128 v[32:35], %[pa]\n\t"
    "ds_read_b128 v[36:39], %[pa] offset:16\n\t"
    "ds_read_b128 v[40:43], %[pa] offset:32\n\t"
    "ds_read_b128 v[44:47], %[pa] offset:48\n\t"
    "ds_read_b128 v[48:51], %[pa] offset:64\n\t"
    "ds_read_b128 v[52:55], %[pa] offset:80\n\t"
    "ds_read_b128 v[56:59], %[pa] offset:96\n\t"
    "ds_read_b128 v[60:63], %[pa] offset:112\n\t"
    "s_waitcnt lgkmcnt(4)\n\t"
    DOTS_A
    "s_waitcnt lgkmcnt(0)\n\t"
    DOTS_B
    RED2
    "s_waitcnt vmcnt(2)\n\t"
    GATES1("v12", "v13", "v14")
    "global_load_dwordx2 v[12:13], %[vorz], %[rzb]\n\t"
    "global_load_dword v14, %[vonb], %[nbb]\n\t"
    "ds_write_b32 %[pw], %[h0] offset:576\n\t"
    "global_store_dword %[voho], %[h0], %[hob]\n\t"
    "s_waitcnt lgkmcnt(0)\n\t"
    "s_barrier\n\t"
    // ================= phase B (odd t): h in buf1 =================
    "ds_read_b128 v[32:35], %[pa] offset:576\n\t"
    "ds_read_b128 v[36:39], %[pa] offset:592\n\t"
    "ds_read_b128 v[40:43], %[pa] offset:608\n\t"
    "ds_read_b128 v[44:47], %[pa] offset:624\n\t"
    "ds_read_b128 v[48:51], %[pa] offset:640\n\t"
    "ds_read_b128 v[52:55], %[pa] offset:656\n\t"
    "ds_read_b128 v[56:59], %[pa] offset:672\n\t"
    "ds_read_b128 v[60:63], %[pa] offset:688\n\t"
    "s_waitcnt lgkmcnt(4)\n\t"
    DOTS_A
    "s_waitcnt lgkmcnt(0)\n\t"
    DOTS_B
    RED2
    "s_waitcnt vmcnt(2)\n\t"
    GATES1("v16", "v17", "v18")
    "global_load_dwordx2 v[16:17], %[vorz], %[rzb] offset:1024\n\t"
    "global_load_dword v18, %[vonb], %[nbb] offset:512\n\t"
    "ds_write_b32 %[pw], %[h0]\n\t"
    "global_store_dword %[voho], %[h0], %[hob] offset:512\n\t"
    "v_add_u32 %[vorz], 2048, %[vorz]\n\t"
    "v_add_u32 %[vonb], 1024, %[vonb]\n\t"
    "v_add_u32 %[voho], 1024, %[voho]\n\t"
    "s_waitcnt lgkmcnt(0)\n\t"
    "s_barrier\n\t"
    "s_sub_u32 %[cnt], %[cnt], 1\n\t"
    "s_cmp_lg_u32 %[cnt], 0\n\t"
    "s_cbranch_scc1 Lrec%=\n\t"
    : [vorz]"+v"(vorz), [vonb]"+v"(vonb), [voho]"+v"(voho), [cnt]"+s"(cnt),
      [h0]"+v"(hp)
    : [wb]"s"(Ws), [rzb]"s"(rz), [nbb]"s"(nb), [hob]"s"(h0out),
      [vow]"v"(vow), [pa]"v"(pa), [pw]"v"(pw), [bh]"v"(bh), [mk]"s"(mk)
    : "memory", "scc",
      "v12","v13","v14","v15","v16","v17","v18","v19",
      "v20","v21","v22","v23","v24","v25","v26","v27","v28","v29","v30","v31",
      "v32","v33","v34","v35","v36","v37","v38","v39","v40","v41","v42","v43",
      "v44","v45","v46","v47","v48","v49","v50","v51","v52","v53","v54","v55",
      "v56","v57","v58","v59","v60","v61","v62","v63","v64","v65","v66","v67",
      "v68","v69","v70","v71","v72","v73","v74","v75","v76","v77","v78","v79",
      "v80","v81","v82","v83","v84","v85","v86","v87","v88","v89","v90","v91",
      "v92","v93","v94","v95","v96","v97","v98","v99","v100","v101","v102",
      "v103","v104","v105","v106","v107","v108","v109","v110","v111","v112",
      "v113","v114","v115","v116","v117","v118","v119","v120","v121","v122",
      "v123","v124","v125","v126","v127","v128","v129","v130","v131","v132",
      "v133","v134","v135","v136","v137","v138","v139","v140","v141","v142",
      "v143","v144","v145","v146","v147","v148","v149","v150","v151","v152",
      "v153","v154","v155","v156","v157","v158","v159","v160","v161","v162",
      "v163","v164","v165","v166","v167","v168","v169","v170","v171","v172",
      "v173","v174","v175","v176","v177","v178","v179","v180","v181","v182",
      "v183","v184","v185","v186","v187","v188","v189","v190","v191","v192",
      "v193","v194","v195","v196","v197","v198","v199","v200","v201","v202",
      "v203","v204","v205","v206","v207","v208","v209","v210","v211","v212",
      "v213","v214","v215","v216","v217","v218","v219","v220","v221","v222",
      "v223","v224","v225","v226","v227","v228","v229","v230","v231","v232",
      "v233","v234","v235","v236","v237","v238","v239","v240","v241","v242",
      "v243","v244","v245","v246","v247","v248","v249","v250","v251","v252",
      "v253","v254","v255");

  if ((cs & 1) == 0) {
    hstate[ul] = hp;
    if (outp) outp[ul] = hp;
  }
}

// barrier-matched idle loop for waves 4-7 of recurrence blocks (1 + CH barriers)
__device__ __forceinline__ void idle_barriers() {
  #pragma unroll 1
  for (int i = 0; i <= CH; ++i)
    asm volatile("s_barrier" ::: "memory");
}

// ============== army phase A: gi0 = Wi0s @ x + bA0 (r15-proven) ==============
__device__ __forceinline__ void role_giA(int rb, int c, const float* __restrict__ x,
                                         const float* __restrict__ Wi0s,
                                         const float* __restrict__ bA0,
                                         float* __restrict__ rz, float* __restrict__ nb) {
  const int tid = threadIdx.x;
  const int u = tid & 127, sb = tid >> 7;
  const int row = rb * 128 + u;
  const f32x4 wa = *(const f32x4*)(Wi0s + (size_t)row * 8);
  const f32x4 wb = *(const f32x4*)(Wi0s + (size_t)row * 8 + 4);
  const float bias = bA0[row];
  const int m = u >> 1, sub = u & 1;
  for (int i = 0; i < CH / 4; ++i) {
    const int tl = sb * (CH / 4) + i;
    const float* xp = x + ((size_t)c * CH + tl) * 8;
    const f32x4 xa = *(const f32x4*)xp;
    const f32x4 xb2 = *(const f32x4*)(xp + 4);
    float acc = bias;
    acc = fmaf(wa.x, xa.x, acc); acc = fmaf(wa.y, xa.y, acc);
    acc = fmaf(wa.z, xa.z, acc); acc = fmaf(wa.w, xa.w, acc);
    acc = fmaf(wb.x, xb2.x, acc); acc = fmaf(wb.y, xb2.y, acc);
    acc = fmaf(wb.z, xb2.z, acc); acc = fmaf(wb.w, xb2.w, acc);
    if (rb < 2) rz[(size_t)tl * 256 + 4 * m + 2 * sub + rb] = acc;
    else        nb[(size_t)tl * 128 + u] = acc;
  }
}

// ============== army phase B: gi1 = Wi1s @ h0 + bA1 (r15-proven) ==============
__device__ __forceinline__ void role_giB(int rb, const float* __restrict__ h0src,
                                         const float* __restrict__ Wi1s,
                                         const float* __restrict__ bA1,
                                         float* __restrict__ rz, float* __restrict__ nb) {
  __shared__ __align__(16) float hsg[2][GS * HDIM];
  const int tid = threadIdx.x, cs = tid & 7, m = tid >> 3;
  const int R0 = rb * 128 + 2 * m, R1 = R0 + 1;
  f32x4 V0[4], V1[4];
  {
    const float* p0 = Wi1s + (size_t)R0 * 128 + 8 * cs;
    const float* p1 = Wi1s + (size_t)R1 * 128 + 8 * cs;
    V0[0] = *(const f32x4*)p0;        V0[1] = *(const f32x4*)(p0 + 4);
    V0[2] = *(const f32x4*)(p0 + 64); V0[3] = *(const f32x4*)(p0 + 68);
    V1[0] = *(const f32x4*)p1;        V1[1] = *(const f32x4*)(p1 + 4);
    V1[2] = *(const f32x4*)(p1 + 64); V1[3] = *(const f32x4*)(p1 + 68);
  }
  const float b0 = bA1[R0], b1 = bA1[R1];

  if (tid < 256) ((f32x4*)hsg[0])[tid] = ((const f32x4*)h0src)[tid];
  __syncthreads();
  int cur = 0;
  for (int gb = 0; gb < CH / GS; ++gb) {
    f32x4 pf;
    const bool hv = (gb + 1 < CH / GS) && (tid < 256);
    if (hv) pf = ((const f32x4*)(h0src + (size_t)(gb + 1) * (GS * HDIM)))[tid];
    #pragma unroll
    for (int s = 0; s < GS; ++s) {
      const float* hb = hsg[cur] + s * HDIM;
      const f32x4 hA = *(const f32x4*)(hb + 8 * cs);
      const f32x4 hB = *(const f32x4*)(hb + 8 * cs + 4);
      const f32x4 hC = *(const f32x4*)(hb + 64 + 8 * cs);
      const f32x4 hD = *(const f32x4*)(hb + 64 + 8 * cs + 4);
      f32x2 d0 = {0.f, 0.f}, d1 = d0;
      pkfma(d0, lo2(V0[0]), lo2(hA)); pkfma(d0, hi2(V0[0]), hi2(hA));
      pkfma(d0, lo2(V0[1]), lo2(hB)); pkfma(d0, hi2(V0[1]), hi2(hB));
      pkfma(d0, lo2(V0[2]), lo2(hC)); pkfma(d0, hi2(V0[2]), hi2(hC));
      pkfma(d0, lo2(V0[3]), lo2(hD)); pkfma(d0, hi2(V0[3]), hi2(hD));
      pkfma(d1, lo2(V1[0]), lo2(hA)); pkfma(d1, hi2(V1[0]), hi2(hA));
      pkfma(d1, lo2(V1[1]), lo2(hB)); pkfma(d1, hi2(V1[1]), hi2(hB));
      pkfma(d1, lo2(V1[2]), lo2(hC)); pkfma(d1, hi2(V1[2]), hi2(hC));
      pkfma(d1, lo2(V1[3]), lo2(hD)); pkfma(d1, hi2(V1[3]), hi2(hD));
      const float a0 = red8(d0.x + d0.y) + b0;
      const float a1 = red8(d1.x + d1.y) + b1;
      if (cs == 0) {
        const int tl = gb * GS + s;
        if (rb < 2) {
          rz[(size_t)tl * 256 + 4 * m + rb] = a0;
          rz[(size_t)tl * 256 + 4 * m + 2 + rb] = a1;
        } else {
          f32x2 nv = {a0, a1};
          *(f32x2*)(nb + (size_t)tl * 128 + 2 * m) = nv;
        }
      }
    }
    if (hv) ((f32x4*)hsg[cur ^ 1])[tid] = pf;
    __syncthreads();
    cur ^= 1;
  }
}

// =============== the pipelined kernel (5 blocks x 512 threads) ===============
__global__ __launch_bounds__(512)
void gru_pipe(const float* __restrict__ x, float* __restrict__ out,
              const float* __restrict__ W0s, const float* __restrict__ W1s,
              const float* __restrict__ Wi0s, const float* __restrict__ Wi1s,
              const float* __restrict__ bA0, const float* __restrict__ bA1,
              const float* __restrict__ bhnS0, const float* __restrict__ bhnS1,
              float* __restrict__ hstate0, float* __restrict__ hstate1,
              float* __restrict__ h0ring, float* __restrict__ gi0rz,
              float* __restrict__ gi0n, float* __restrict__ gi1rz,
              float* __restrict__ gi1n, float* __restrict__ h1dump, int k) {
  const int bid = blockIdx.x;
  if (bid == 0) {
    const int c = k - 1;
    if (c >= 0 && c < NC) {
      if (threadIdx.x < 256)
        rec_asm(W0s, bhnS0,
                gi0rz + (size_t)(c & 1) * CH * 256, gi0n + (size_t)(c & 1) * CH * 128,
                hstate0, h0ring + (size_t)(c & 1) * CH * HDIM, nullptr, c);
      else
        idle_barriers();
    }
  } else if (bid == 1) {
    const int c = k - 3;
    if (c >= 0 && c < NC) {
      if (threadIdx.x < 256)
        rec_asm(W1s, bhnS1,
                gi1rz + (size_t)(c & 1) * CH * 256, gi1n + (size_t)(c & 1) * CH * 128,
                hstate1, h1dump, (c == NC - 1) ? out : nullptr, c);
      else
        idle_barriers();
    }
  } else {
    const int rb = bid - 2;
    if (k < NC)
      role_giA(rb, k, x, Wi0s, bA0,
               gi0rz + (size_t)(k & 1) * CH * 256, gi0n + (size_t)(k & 1) * CH * 128);
    const int cb = k - 2;
    if (cb >= 0 && cb < NC)
      role_giB(rb, h0ring + (size_t)(cb & 1) * CH * HDIM, Wi1s, bA1,
               gi1rz + (size_t)(cb & 1) * CH * 256, gi1n + (size_t)(cb & 1) * CH * 128);
  }
}

extern "C" void kernel_launch(void* const* d_in, const int* in_sizes, int n_in,
                              void* d_out, int out_size, void* d_ws, size_t ws_size,
                              hipStream_t stream) {
  (void)in_sizes; (void)n_in; (void)out_size; (void)ws_size;
  const float* x     = (const float*)d_in[0];
  const float* w_ih0 = (const float*)d_in[1];
  const float* w_hh0 = (const float*)d_in[2];
  const float* b_ih0 = (const float*)d_in[3];
  const float* b_hh0 = (const float*)d_in[4];
  const float* w_ih1 = (const float*)d_in[5];
  const float* w_hh1 = (const float*)d_in[6];
  const float* b_ih1 = (const float*)d_in[7];
  const float* b_hh1 = (const float*)d_in[8];
  float* out = (float*)d_out;

  float* p = (float*)d_ws;
  float* W0s    = p; p += 49152;
  float* W1s    = p; p += 49152;
  float* Wi1s   = p; p += 49152;
  float* Wi0s   = p; p += 3072;
  float* bA0    = p; p += 384;
  float* bA1    = p; p += 384;
  float* bhnS0  = p; p += 128;
  float* bhnS1  = p; p += 128;
  float* hstate0 = p; p += 128;
  float* hstate1 = p; p += 128;
  float* h0ring  = p; p += (size_t)2 * CH * 128;
  float* gi0rz   = p; p += (size_t)2 * CH * 256;
  float* gi0n    = p; p += (size_t)2 * CH * 128;
  float* gi1rz   = p; p += (size_t)2 * CH * 256;
  float* gi1n    = p; p += (size_t)2 * CH * 128;
  float* h1dump  = p; p += (size_t)CH * 128;       // l1 h-store sink (unread)

  hipLaunchKernelGGL(gru_prep, dim3(192), dim3(256), 0, stream,
                     w_ih0, w_hh0, b_ih0, b_hh0, w_ih1, w_hh1, b_ih1, b_hh1,
                     W0s, W1s, Wi0s, Wi1s, bA0, bA1, bhnS0, bhnS1);
  for (int k = 0; k <= NC + 2; ++k) {
    hipLaunchKernelGGL(gru_pipe, dim3(5), dim3(512), 0, stream,
                       x, out, W0s, W1s, Wi0s, Wi1s, bA0, bA1, bhnS0, bhnS1,
                       hstate0, hstate1, h0ring, gi0rz, gi0n, gi1rz, gi1n,
                       h1dump, k);
  }
}